// Round 12
// baseline (671.606 us; speedup 1.0000x reference)
//
#include <hip/hip_runtime.h>
#include <math.h>

#define BB 8
#define NN 2048
#define DD 512
#define KK 16
#define BN (BB*NN)

#define QT 64
#define JSPLIT 4
#define JRANGE (NN/JSPLIT)      // 512 candidates per block
#define MM (16*JSPLIT)          // 64 candidates per query into phase-2
#define SIMP 68                 // simb row stride (floats)

#define KSPLIT 384              // OpenBLAS SGEMM_DEFAULT_Q (ZEN) — DO NOT CHANGE

#define OUT1 (BN*3)
#define OUT2 (2*BN*3)
#define OUT3 (3*BN*3)

typedef __attribute__((ext_vector_type(8))) short bf16x8;
typedef __attribute__((ext_vector_type(4))) float f32x4;

__device__ inline unsigned short cvt_bf16(float f) {   // RNE, finite inputs
    unsigned int u = __float_as_uint(f);
    return (unsigned short)((u + 0x7fffu + ((u >> 16) & 1u)) >> 16);
}

// async global->LDS, 16B per lane; lds must be wave-uniform base (HW adds lane*16)
__device__ inline void gload_lds16(const unsigned short* g, unsigned short* lds) {
    __builtin_amdgcn_global_load_lds((const __attribute__((address_space(1))) void*)g,
                                     (__attribute__((address_space(3))) void*)lds,
                                     16, 0, 0);
}

// ---------------- Kernel 1: numpy-bit-exact f32 row norms (scalar-8 base) -----
// VERIFIED r8. DO NOT CHANGE ARITHMETIC.
__global__ __launch_bounds__(256) void k_norm_np(const float* __restrict__ ffq,
                                                 const float* __restrict__ ffp,
                                                 float* __restrict__ normq,
                                                 float* __restrict__ normp,
                                                 float* __restrict__ rnp32) {
    const int row = blockIdx.x * 32 + (threadIdx.x >> 3);
    const int j   = threadIdx.x & 7;
    const bool isQ = row < BN;
    const int r = isQ ? row : row - BN;
    const float* x = (isQ ? ffq : ffp) + (size_t)r * DD;

    float B[4];
#pragma unroll
    for (int t = 0; t < 4; ++t) {
        const float* xb = x + t * 128;
        float e = xb[j];
        float rj = __fmul_rn(e, e);
#pragma unroll
        for (int i = 1; i < 16; ++i) {
            float v = xb[8 * i + j];
            rj = __fadd_rn(rj, __fmul_rn(v, v));
        }
        float s = __fadd_rn(rj, __shfl_xor(rj, 1, 8));
        float u = __fadd_rn(s,  __shfl_xor(s,  2, 8));
        float w = __fadd_rn(u,  __shfl_xor(u,  4, 8));
        B[t] = w;
    }
    if (j == 0) {
        float norm2 = __fadd_rn(__fadd_rn(B[0], B[1]), __fadd_rn(B[2], B[3]));
        float nrm = __fsqrt_rn(norm2);
        if (isQ) { normq[r] = nrm; }
        else {
            normp[r] = nrm;
            rnp32[r] = 1.0f / __fadd_rn(nrm, 1e-8f);
        }
    }
}

// ---------------- Kernel 1b: normalized f32 (exact bits) + bf16 copies --------
__global__ __launch_bounds__(256) void k_normalize(const float* __restrict__ ffq,
                                                   const float* __restrict__ ffp,
                                                   const float* __restrict__ normq,
                                                   const float* __restrict__ normp,
                                                   float* __restrict__ fqn,
                                                   float* __restrict__ fpn,
                                                   unsigned short* __restrict__ fqb,
                                                   unsigned short* __restrict__ fpb) {
    const size_t e4 = ((size_t)blockIdx.x * 256 + threadIdx.x) * 4;
    if (e4 >= (size_t)BN * DD) return;
    const int row = (int)(e4 >> 9);
    {
        float4 v = *(const float4*)(ffq + e4);
        float den = __fadd_rn(normq[row], 1e-8f);
        float4 o;
        o.x = __fdiv_rn(v.x, den); o.y = __fdiv_rn(v.y, den);
        o.z = __fdiv_rn(v.z, den); o.w = __fdiv_rn(v.w, den);
        *(float4*)(fqn + e4) = o;
        ushort4 b; b.x = cvt_bf16(o.x); b.y = cvt_bf16(o.y);
        b.z = cvt_bf16(o.z); b.w = cvt_bf16(o.w);
        *(ushort4*)(fqb + e4) = b;
    }
    {
        float4 v = *(const float4*)(ffp + e4);
        float den = __fadd_rn(normp[row], 1e-8f);
        float4 o;
        o.x = __fdiv_rn(v.x, den); o.y = __fdiv_rn(v.y, den);
        o.z = __fdiv_rn(v.z, den); o.w = __fdiv_rn(v.w, den);
        *(float4*)(fpn + e4) = o;
        ushort4 b; b.x = cvt_bf16(o.x); b.y = cvt_bf16(o.y);
        b.z = cvt_bf16(o.z); b.w = cvt_bf16(o.w);
        *(ushort4*)(fpb + e4) = b;
    }
}

// ---------------- Kernel 2 (fast): bf16 MFMA scoring + per-split top-16 -------
// r16: r4 structure (drain loop, CK=128, launch_bounds(256,4)) — measured
// optimum vs r5-r8 variants. r17: per-chunk A-frag loads with opaque offset
// (spills eliminated). r18: branchless bitonic top-16 on packed u64 keys
// (bit-identical order: value desc, index asc). 426us total at r18.
// r11 staging: B tile in LDS via global_load_lds width-16, XOR-block swizzle
// both sides -> conflict-free (PMC: 0).
// C layout (m89): col=lane&15, row=(lane>>4)*4+reg.
#define CK 128                   // staged K-chunk (bf16 elems); DD/CK = 4
__global__ __launch_bounds__(256, 4) void k_phase1_m(const unsigned short* __restrict__ fqb,
                                                     const unsigned short* __restrict__ fpb,
                                                     unsigned short* __restrict__ cand) {
    __shared__ __align__(16) float simb[QT * SIMP];
    __shared__ __align__(16) unsigned short Bst[64 * CK];   // 16 KB staged B chunk

    const int b  = blockIdx.x & 7;
    const int i0 = ((blockIdx.x >> 3) & 31) * QT;
    const int js = blockIdx.x >> 8;
    const int tid = threadIdx.x;
    const int w = tid >> 6, lane = tid & 63;
    const int n16 = lane & 15, quad = lane >> 4;

    const unsigned short* Aq = fqb + ((size_t)b * NN + i0 + w * 16 + n16) * DD + quad * 8;

    // running top-16 as packed keys, ascending (slot 15 = best). 0 = -inf.
    unsigned long long ktop[16];
#pragma unroll
    for (int r = 0; r < 16; ++r) ktop[r] = 0ull;

    const int qq = tid >> 2;
    const int st = tid & 3;
    const size_t bNN = (size_t)b * NN;

    for (int jt = 0; jt < JRANGE / 64; ++jt) {   // 8 j-tiles of 64
        const int j0g = js * JRANGE + jt * 64;

        f32x4 acc[4];
#pragma unroll
        for (int ct = 0; ct < 4; ++ct) acc[ct] = (f32x4){0.f, 0.f, 0.f, 0.f};

        for (int kc = 0; kc < 4; ++kc) {          // K chunks of 128
            __syncthreads();   // prev chunk's ds_reads / prev tile's sel reads done
            // stage: call l covers LDS rows (w*4+l)*4+quad, block col n16
            // data at LDS block (r, n16) comes from global block (r, n16^(r&15))
#pragma unroll
            for (int l = 0; l < 4; ++l) {
                const int r  = (w * 4 + l) * 4 + quad;
                const int sb = n16 ^ (r & 15);
                const unsigned short* gsrc =
                    fpb + (bNN + j0g + r) * DD + kc * CK + sb * 8;
                gload_lds16(gsrc, &Bst[(w * 4 + l) * 512]);   // 1 KB per call
            }
            // A frags for this chunk only (opaque offset: not hoistable).
            int koff = kc * 128;
            asm volatile("" : "+v"(koff));
            bf16x8 a0 = *(const bf16x8*)(Aq + koff);
            bf16x8 a1 = *(const bf16x8*)(Aq + koff + 32);
            bf16x8 a2 = *(const bf16x8*)(Aq + koff + 64);
            bf16x8 a3 = *(const bf16x8*)(Aq + koff + 96);
            __syncthreads();   // barrier drains vmcnt -> LDS chunk + A frags ready
#pragma unroll
            for (int k4 = 0; k4 < 4; ++k4) {
                const bf16x8 af = (k4 == 0) ? a0 : (k4 == 1) ? a1 : (k4 == 2) ? a2 : a3;
#pragma unroll
                for (int ct = 0; ct < 4; ++ct) {
                    const int r  = ct * 16 + n16;
                    const int cb = (k4 * 4 + quad) ^ (r & 15);
                    bf16x8 bfr = *(const bf16x8*)&Bst[r * CK + cb * 8];
                    acc[ct] = __builtin_amdgcn_mfma_f32_16x16x32_bf16(
                        af, bfr, acc[ct], 0, 0, 0);
                }
            }
        }

        __syncthreads();
#pragma unroll
        for (int ct = 0; ct < 4; ++ct)
#pragma unroll
            for (int r = 0; r < 4; ++r)
                simb[(w * 16 + quad * 4 + r) * SIMP + ct * 16 + n16] = acc[ct][r];
        __syncthreads();

        // ---- r18 selection: branchless bitonic top-16 on packed u64 keys ----
        unsigned long long nk[16];
#pragma unroll
        for (int t4 = 0; t4 < 4; ++t4) {
            const float4 v4 = *(const float4*)&simb[qq * SIMP + st * 16 + t4 * 4];
            const float vv[4] = {v4.x, v4.y, v4.z, v4.w};
#pragma unroll
            for (int u = 0; u < 4; ++u) {
                const float cvf = __fadd_rn(vv[u], 0.0f);     // -0 -> +0
                const unsigned int ub  = __float_as_uint(cvf);
                const unsigned int ord = ub ^ (((unsigned int)((int)ub >> 31)) | 0x80000000u);
                const unsigned int jg  = (unsigned int)(j0g + st * 16 + t4 * 4 + u);
                nk[t4 * 4 + u] = ((unsigned long long)ord << 32)
                               | (unsigned long long)(~jg);
            }
        }
#pragma unroll
        for (int k = 2; k <= 16; k <<= 1) {
#pragma unroll
            for (int j = k >> 1; j > 0; j >>= 1) {
#pragma unroll
                for (int i = 0; i < 16; ++i) {
                    const int l = i ^ j;
                    if (l > i) {
                        const bool up = ((i & k) == 0);
                        const unsigned long long a = nk[i], bq = nk[l];
                        const bool sw = up ? (a > bq) : (a < bq);
                        nk[i] = sw ? bq : a;
                        nk[l] = sw ? a : bq;
                    }
                }
            }
        }
        unsigned long long mg[16];
#pragma unroll
        for (int i = 0; i < 16; ++i) {
            const unsigned long long a = ktop[i], bq = nk[15 - i];
            mg[i] = (a > bq) ? a : bq;
        }
#pragma unroll
        for (int j = 8; j > 0; j >>= 1) {
#pragma unroll
            for (int i = 0; i < 16; ++i) {
                const int l = i ^ j;
                if (l > i) {
                    const unsigned long long a = mg[i], bq = mg[l];
                    const bool sw = a > bq;
                    mg[i] = sw ? bq : a;
                    mg[l] = sw ? a : bq;
                }
            }
        }
#pragma unroll
        for (int i = 0; i < 16; ++i) ktop[i] = mg[i];
    }

    // merge 4 sorted 16-lists (lanes st=0..3 of query qq) -> split top-16.
    __syncthreads();
    int p = 15;
    const size_t base = ((size_t)b * NN + i0 + qq) * MM + (size_t)js * 16;
    for (int m = 0; m < 16; ++m) {
        const unsigned long long myk = (p >= 0) ? ktop[p] : 0ull;
        unsigned long long wk = myk;
        unsigned long long ok;
        ok = __shfl_xor(wk, 1, 4); if (ok > wk) wk = ok;
        ok = __shfl_xor(wk, 2, 4); if (ok > wk) wk = ok;
        if (p >= 0 && myk == wk) --p;
        if (st == 0) cand[base + m] = (unsigned short)(~(unsigned int)wk);
    }
}

// ---------------- Kernel 2 (fallback): r9 fp32 GEMM phase-1 -------------------
#define JTILE 64
#define BK 16
#define LDP 68
__global__ __launch_bounds__(256, 4) void k_phase1_v(const float* __restrict__ ffq,
                                                     const float* __restrict__ ffp,
                                                     const float* __restrict__ rnp32,
                                                     unsigned short* __restrict__ cand) {
    __shared__ __align__(16) float As[BK * LDP];
    __shared__ __align__(16) float Bs[BK * LDP];
    __shared__ __align__(16) float simb[QT * SIMP];

    const int b  = blockIdx.x & 7;
    const int i0 = ((blockIdx.x >> 3) & 31) * QT;
    const int js = blockIdx.x >> 8;
    const int tid = threadIdx.x;
    const int tx = tid & 15, ty = tid >> 4;

    const float* Abase = ffq + ((size_t)b * NN + i0) * DD;
    const float* Bbase = ffp + (size_t)b * NN * DD;

    float tv[16]; int tix[16];
#pragma unroll
    for (int r = 0; r < 16; ++r) { tv[r] = -INFINITY; tix[r] = -1; }

    const int lrow = tid >> 2;
    const int lseg = (tid & 3) * 4;
    const int qq = tid >> 2;
    const int st = tid & 3;

    for (int jt = 0; jt < JRANGE / JTILE; ++jt) {
        const int j0 = js * JRANGE + jt * JTILE;
        float acc[4][4];
#pragma unroll
        for (int r = 0; r < 4; ++r)
#pragma unroll
            for (int c = 0; c < 4; ++c) acc[r][c] = 0.0f;

        for (int kt = 0; kt < DD / BK; ++kt) {
            const int k0 = kt * BK;
            __syncthreads();
            float4 av = *(const float4*)(Abase + (size_t)lrow * DD + k0 + lseg);
            float4 bv = *(const float4*)(Bbase + (size_t)(j0 + lrow) * DD + k0 + lseg);
            As[(lseg + 0) * LDP + lrow] = av.x; As[(lseg + 1) * LDP + lrow] = av.y;
            As[(lseg + 2) * LDP + lrow] = av.z; As[(lseg + 3) * LDP + lrow] = av.w;
            Bs[(lseg + 0) * LDP + lrow] = bv.x; Bs[(lseg + 1) * LDP + lrow] = bv.y;
            Bs[(lseg + 2) * LDP + lrow] = bv.z; Bs[(lseg + 3) * LDP + lrow] = bv.w;
            __syncthreads();
#pragma unroll
            for (int kk = 0; kk < BK; ++kk) {
                const float4 a4 = *(const float4*)&As[kk * LDP + ty * 4];
                const float4 b4 = *(const float4*)&Bs[kk * LDP + tx * 4];
                const float ar[4] = {a4.x, a4.y, a4.z, a4.w};
                const float br[4] = {b4.x, b4.y, b4.z, b4.w};
#pragma unroll
                for (int r = 0; r < 4; ++r)
#pragma unroll
                    for (int c = 0; c < 4; ++c)
                        acc[r][c] = fmaf(ar[r], br[c], acc[r][c]);
            }
        }
        float rp[4];
#pragma unroll
        for (int c = 0; c < 4; ++c) rp[c] = rnp32[b * NN + j0 + tx * 4 + c];
#pragma unroll
        for (int r = 0; r < 4; ++r) {
            float4 v4;
            v4.x = acc[r][0] * rp[0]; v4.y = acc[r][1] * rp[1];
            v4.z = acc[r][2] * rp[2]; v4.w = acc[r][3] * rp[3];
            *(float4*)&simb[(ty * 4 + r) * SIMP + tx * 4] = v4;
        }
        __syncthreads();

#pragma unroll
        for (int t = 0; t < 16; ++t) {
            const int jl = st * 16 + t;
            const float v = simb[qq * SIMP + jl];
            const int jg = j0 + jl;
            if (v > tv[0]) {
#pragma unroll
                for (int r = 0; r < 15; ++r) {
                    const bool up = tv[r + 1] < v;
                    const float nv = up ? tv[r + 1] : ((tv[r] < v) ? v : tv[r]);
                    const int   ni = up ? tix[r + 1] : ((tv[r] < v) ? jg : tix[r]);
                    tv[r] = nv; tix[r] = ni;
                }
                if (tv[15] < v) { tv[15] = v; tix[15] = jg; }
            }
        }
        __syncthreads();
    }

    int p = 15;
    const size_t base = ((size_t)b * NN + i0 + qq) * MM + (size_t)js * 16;
    for (int m = 0; m < 16; ++m) {
        float cv = (p >= 0) ? tv[p] : -INFINITY;
        int   ci = (p >= 0) ? tix[p] : -1;
        float ov; int oi;
        ov = __shfl_xor(cv, 1, 4); oi = __shfl_xor(ci, 1, 4);
        if (ov > cv || (ov == cv && (unsigned)oi < (unsigned)ci)) { cv = ov; ci = oi; }
        ov = __shfl_xor(cv, 2, 4); oi = __shfl_xor(ci, 2, 4);
        if (ov > cv || (ov == cv && (unsigned)oi < (unsigned)ci)) { cv = ov; ci = oi; }
        if (p >= 0 && tv[p] == cv && tix[p] == ci) --p;
        if (st == 0) cand[base + m] = (unsigned short)ci;
    }
}

// ---------------- 3x3 inverse (adjugate) apply ----------------
__device__ inline void inv3_apply(const double* a, double x0, double x1, double x2,
                                  double& y0, double& y1, double& y2) {
    double c00 = a[4]*a[8] - a[5]*a[7];
    double c01 = a[2]*a[7] - a[1]*a[8];
    double c02 = a[1]*a[5] - a[2]*a[4];
    double c10 = a[5]*a[6] - a[3]*a[8];
    double c11 = a[0]*a[8] - a[2]*a[6];
    double c12 = a[2]*a[3] - a[0]*a[5];
    double c20 = a[3]*a[7] - a[4]*a[6];
    double c21 = a[1]*a[6] - a[0]*a[7];
    double c22 = a[0]*a[4] - a[1]*a[3];
    double det = a[0]*c00 + a[1]*c10 + a[2]*c20;
    double id = 1.0 / det;
    y0 = (c00*x0 + c01*x1 + c02*x2) * id;
    y1 = (c10*x0 + c11*x1 + c12*x2) * id;
    y2 = (c20*x0 + c21*x1 + c22*x2) * id;
}

// =============== shared phase-2 body (64-thread blocks, reg-streamed) =========
// VERIFIED r8 RESCORE arithmetic: two ascending-d FMA chains split at d=384,
// one rounded add. Tie: value desc, index asc. DO NOT CHANGE CHAIN ORDER.
//
// r19: one wave per query; lane t owns candidate t. Row streamed through a
// double-buffered 16xfloat4 register window (ping-pong A/B, static indexing)
// and chained DIRECTLY from registers — no LDS staging, no rescore barriers
// (r11 PMC: only wave 0 computed; 3 waves + 16 barriers were overhead).
// Chain ops are sequence-identical to r8 -> identical sv/ranking/indices.
// Pooling per-d k-ascending unchanged (bit-exact). W reduction order changes
// (8-term serial + 1-wave tree vs 2-term + 4-wave) — continuous ~1e-6 effect
// on q_refine only, after all index decisions; tolerance >= 2^-7.
template <bool PRE>   // PRE: normalized arrays precomputed (fast path)
__device__ inline void phase2_body(
        const float* __restrict__ qin, const float* __restrict__ ffq,
        const float* __restrict__ ffp, const float* __restrict__ R1,
        const float* __restrict__ R2, const int* __restrict__ cent,
        const float* __restrict__ W, const float* __restrict__ bvec,
        const float* __restrict__ normq, const float* __restrict__ normp,
        const float* __restrict__ fqn, const float* __restrict__ fpn,
        const unsigned short* __restrict__ cand, float* __restrict__ out) {
    static_assert(KSPLIT == 384, "chunk split at c=6 assumes KSPLIT==384");
    const int b = blockIdx.x & 7;
    const int i = blockIdx.x >> 3;
    const int t = threadIdx.x;            // 0..63, lane == thread
    const size_t qi = (size_t)b * NN + i;

    __shared__ __align__(16) float sbuf[2 * DD];  // sfqn, then meanf/maxf overlay
    __shared__ float sv[MM];
    __shared__ int cjs[MM];
    __shared__ int sel[KK];
    float* const sfqn  = sbuf;
    float* const meanf = sbuf;            // sfqn dead after chains
    float* const maxf  = sbuf + DD;

    if (PRE) {
        for (int d = t; d < DD; d += 64)
            sfqn[d] = fqn[qi * DD + d];
    } else {
        const float qden = __fadd_rn(normq[qi], 1e-8f);
        for (int d = t; d < DD; d += 64)
            sfqn[d] = __fdiv_rn(ffq[qi * DD + d], qden);
    }
    const int j = (int)cand[qi * MM + t];
    cjs[t] = j;
    const float pd = PRE ? 1.0f : __fadd_rn(normp[(size_t)b * NN + j], 1e-8f);
    const float* fprow = (PRE ? fpn : ffp) + ((size_t)b * NN + j) * DD;
    __syncthreads();                      // sfqn + cjs ready

    // ---- rescore: per-lane register-streamed row, bit-exact chains ----
    float acc1 = 0.0f, acc2 = 0.0f;
    float4 bufA[16], bufB[16];

    auto ldc = [&](float4* P, int c) {    // load chunk c (d = c*64 .. +63)
#pragma unroll
        for (int m = 0; m < 16; ++m)
            P[m] = *(const float4*)(fprow + c * 64 + m * 4);
    };
    auto chn = [&](const float4* P, int c, float& acc) {   // d-ascending chain
        const int d0 = c * 64;
        if (PRE) {
#pragma unroll
            for (int m = 0; m < 16; ++m) {
                acc = fmaf(sfqn[d0 + m * 4 + 0], P[m].x, acc);
                acc = fmaf(sfqn[d0 + m * 4 + 1], P[m].y, acc);
                acc = fmaf(sfqn[d0 + m * 4 + 2], P[m].z, acc);
                acc = fmaf(sfqn[d0 + m * 4 + 3], P[m].w, acc);
            }
        } else {
#pragma unroll
            for (int m = 0; m < 16; ++m) {
                acc = fmaf(sfqn[d0 + m * 4 + 0], __fdiv_rn(P[m].x, pd), acc);
                acc = fmaf(sfqn[d0 + m * 4 + 1], __fdiv_rn(P[m].y, pd), acc);
                acc = fmaf(sfqn[d0 + m * 4 + 2], __fdiv_rn(P[m].z, pd), acc);
                acc = fmaf(sfqn[d0 + m * 4 + 3], __fdiv_rn(P[m].w, pd), acc);
            }
        }
    };

    ldc(bufA, 0);
#pragma unroll
    for (int h = 0; h < 4; ++h) {
        const int c0 = 2 * h;             // even chunk: use A, prefetch -> B
        ldc(bufB, c0 + 1);                // c0+1 <= 7 always
        chn(bufA, c0, (c0 < 6) ? acc1 : acc2);
        const int c1 = 2 * h + 1;         // odd chunk: use B, prefetch -> A
        if (h < 3) ldc(bufA, c1 + 1);
        chn(bufB, c1, (c1 < 6) ? acc1 : acc2);
    }
    sv[t] = __fadd_rn(acc1, acc2);
    __syncthreads();

    // ---- rank (identical semantics: value desc, index asc) ----
    {
        const float v = sv[t];
        int rank = 0;
        for (int tt = 0; tt < MM; ++tt) {
            const float vt = sv[tt]; const int jo = cjs[tt];
            rank += (vt > v) || (vt == v && jo < j);
        }
        if (rank < KK) {
            sel[rank] = j;
            out[(size_t)OUT3 + qi * KK + rank] = (float)j;
        }
    }
    __syncthreads();

    // ---- pooling (per-d, k ascending — unchanged order) ----
    for (int d = t; d < DD; d += 64) {
        float sum = 0.0f, mx = -INFINITY;
#pragma unroll
        for (int k = 0; k < KK; ++k) {
            float v = ffp[((size_t)b * NN + sel[k]) * DD + d];
            sum += v; mx = fmaxf(mx, v);
        }
        meanf[d] = sum * (1.0f / 16.0f);
        maxf[d]  = mx;
    }
    __syncthreads();

    // ---- W refine ----
    float a0 = 0.f, a1 = 0.f, a2 = 0.f;
    for (int d = t; d < DD; d += 64) {
        const float x = ffq[qi * DD + d], m = meanf[d], mx = maxf[d];
        a0 = fmaf(W[d],        x, a0); a0 = fmaf(W[512 + d],        m, a0); a0 = fmaf(W[1024 + d],        mx, a0);
        a1 = fmaf(W[1536 + d], x, a1); a1 = fmaf(W[1536 + 512 + d], m, a1); a1 = fmaf(W[1536 + 1024 + d], mx, a1);
        a2 = fmaf(W[3072 + d], x, a2); a2 = fmaf(W[3072 + 512 + d], m, a2); a2 = fmaf(W[3072 + 1024 + d], mx, a2);
    }
#pragma unroll
    for (int off = 32; off > 0; off >>= 1) {
        a0 += __shfl_down(a0, off, 64);
        a1 += __shfl_down(a1, off, 64);
        a2 += __shfl_down(a2, off, 64);
    }

    if (t == 0) {
        double v0 = (double)bvec[0] + a0;
        double v1 = (double)bvec[1] + a1;
        double v2 = (double)bvec[2] + a2;
        double r1[9], r2[9];
#pragma unroll
        for (int u = 0; u < 9; ++u) { r1[u] = R1[qi * 9 + u]; r2[u] = R2[qi * 9 + u]; }
        double u0, u1, u2, w0, w1, w2;
        inv3_apply(r1, v0, v1, v2, u0, u1, u2);
        inv3_apply(r2, u0, u1, u2, w0, w1, w2);
        const float mask = (cent[qi] >= NN) ? 1.0f : 0.0f;
        const float q0 = qin[qi * 3 + 0], q1 = qin[qi * 3 + 1], q2 = qin[qi * 3 + 2];
        out[qi * 3 + 0] = q0; out[qi * 3 + 1] = q1; out[qi * 3 + 2] = q2;
        const float o0 = q0 + (float)w0 * mask;
        const float o1 = q1 + (float)w1 * mask;
        const float o2 = q2 + (float)w2 * mask;
        out[OUT1 + qi * 3 + 0] = o0; out[OUT1 + qi * 3 + 1] = o1; out[OUT1 + qi * 3 + 2] = o2;
        out[OUT2 + qi * 3 + 0] = o0; out[OUT2 + qi * 3 + 1] = o1; out[OUT2 + qi * 3 + 2] = o2;
    }
}

__global__ __launch_bounds__(64) void k_phase2_f(
        const float* qin, const float* ffq, const float* ffp, const float* R1,
        const float* R2, const int* cent, const float* W, const float* bvec,
        const float* fqn, const float* fpn, const unsigned short* cand, float* out) {
    phase2_body<true>(qin, ffq, ffp, R1, R2, cent, W, bvec,
                      nullptr, nullptr, fqn, fpn, cand, out);
}

__global__ __launch_bounds__(64) void k_phase2_v(
        const float* qin, const float* ffq, const float* ffp, const float* R1,
        const float* R2, const int* cent, const float* W, const float* bvec,
        const float* normq, const float* normp, const unsigned short* cand, float* out) {
    phase2_body<false>(qin, ffq, ffp, R1, R2, cent, W, bvec,
                       normq, normp, nullptr, nullptr, cand, out);
}

extern "C" void kernel_launch(void* const* d_in, const int* in_sizes, int n_in,
                              void* d_out, int out_size, void* d_ws, size_t ws_size,
                              hipStream_t stream) {
    (void)in_sizes; (void)n_in; (void)out_size;
    const float* q   = (const float*)d_in[1];
    const float* ffp = (const float*)d_in[2];
    const float* ffq = (const float*)d_in[3];
    const float* R1  = (const float*)d_in[4];
    const float* R2  = (const float*)d_in[5];
    const int*   ct  = (const int*)d_in[6];
    const float* W   = (const float*)d_in[7];
    const float* bb  = (const float*)d_in[8];
    float* out = (float*)d_out;

    float* normq = (float*)d_ws;                               // BN
    float* normp = normq + BN;                                 // BN
    float* rnp32 = normp + BN;                                 // BN
    unsigned short* cand = (unsigned short*)(rnp32 + BN);      // BN*MM u16
    float* fqn = (float*)(cand + (size_t)BN * MM);             // BN*DD
    float* fpn = fqn + (size_t)BN * DD;                        // BN*DD
    unsigned short* fqb = (unsigned short*)(fpn + (size_t)BN * DD);  // BN*DD u16
    unsigned short* fpb = fqb + (size_t)BN * DD;               // BN*DD u16

    const size_t need = (size_t)BN * (35 * 4 + 2 * DD * 4 + 2 * DD * 2);

    k_norm_np<<<dim3((2 * BN) / 32), dim3(256), 0, stream>>>(ffq, ffp, normq, normp, rnp32);

    if (ws_size >= need) {
        k_normalize<<<dim3((BN * DD) / 1024), dim3(256), 0, stream>>>(
            ffq, ffp, normq, normp, fqn, fpn, fqb, fpb);
        k_phase1_m<<<dim3(BB * (NN / QT) * JSPLIT), dim3(256), 0, stream>>>(fqb, fpb, cand);
        k_phase2_f<<<dim3(BB * NN), dim3(64), 0, stream>>>(q, ffq, ffp, R1, R2, ct, W, bb,
                                                           fqn, fpn, cand, out);
    } else {
        k_phase1_v<<<dim3(BB * (NN / QT) * JSPLIT), dim3(256), 0, stream>>>(ffq, ffp, rnp32, cand);
        k_phase2_v<<<dim3(BB * NN), dim3(64), 0, stream>>>(q, ffq, ffp, R1, R2, ct, W, bb,
                                                           normq, normp, cand, out);
    }
}

// Round 14
// 430.987 us; speedup vs baseline: 1.5583x; 1.5583x over previous
//
#include <hip/hip_runtime.h>
#include <math.h>

#define BB 8
#define NN 2048
#define DD 512
#define KK 16
#define BN (BB*NN)

#define QT 64
#define JSPLIT 4
#define JRANGE (NN/JSPLIT)      // 512 candidates per block
#define MM (16*JSPLIT)          // 64 candidates per query into phase-2
#define SIMP 68                 // simb row stride (floats)

#define KSPLIT 384              // OpenBLAS SGEMM_DEFAULT_Q (ZEN) — DO NOT CHANGE

#define OUT1 (BN*3)
#define OUT2 (2*BN*3)
#define OUT3 (3*BN*3)

typedef __attribute__((ext_vector_type(8))) short bf16x8;
typedef __attribute__((ext_vector_type(4))) float f32x4;

__device__ inline unsigned short cvt_bf16(float f) {   // RNE, finite inputs
    unsigned int u = __float_as_uint(f);
    return (unsigned short)((u + 0x7fffu + ((u >> 16) & 1u)) >> 16);
}

// async global->LDS, 16B per lane; lds must be wave-uniform base (HW adds lane*16)
__device__ inline void gload_lds16(const unsigned short* g, unsigned short* lds) {
    __builtin_amdgcn_global_load_lds((const __attribute__((address_space(1))) void*)g,
                                     (__attribute__((address_space(3))) void*)lds,
                                     16, 0, 0);
}

// ---------------- Kernel 1: numpy-bit-exact f32 row norms (scalar-8 base) -----
// VERIFIED r8. DO NOT CHANGE ARITHMETIC.
__global__ __launch_bounds__(256) void k_norm_np(const float* __restrict__ ffq,
                                                 const float* __restrict__ ffp,
                                                 float* __restrict__ normq,
                                                 float* __restrict__ normp,
                                                 float* __restrict__ rnp32) {
    const int row = blockIdx.x * 32 + (threadIdx.x >> 3);
    const int j   = threadIdx.x & 7;
    const bool isQ = row < BN;
    const int r = isQ ? row : row - BN;
    const float* x = (isQ ? ffq : ffp) + (size_t)r * DD;

    float B[4];
#pragma unroll
    for (int t = 0; t < 4; ++t) {
        const float* xb = x + t * 128;
        float e = xb[j];
        float rj = __fmul_rn(e, e);
#pragma unroll
        for (int i = 1; i < 16; ++i) {
            float v = xb[8 * i + j];
            rj = __fadd_rn(rj, __fmul_rn(v, v));
        }
        float s = __fadd_rn(rj, __shfl_xor(rj, 1, 8));
        float u = __fadd_rn(s,  __shfl_xor(s,  2, 8));
        float w = __fadd_rn(u,  __shfl_xor(u,  4, 8));
        B[t] = w;
    }
    if (j == 0) {
        float norm2 = __fadd_rn(__fadd_rn(B[0], B[1]), __fadd_rn(B[2], B[3]));
        float nrm = __fsqrt_rn(norm2);
        if (isQ) { normq[r] = nrm; }
        else {
            normp[r] = nrm;
            rnp32[r] = 1.0f / __fadd_rn(nrm, 1e-8f);
        }
    }
}

// ---------------- Kernel 1b: normalized f32 (exact bits) + bf16 copies --------
__global__ __launch_bounds__(256) void k_normalize(const float* __restrict__ ffq,
                                                   const float* __restrict__ ffp,
                                                   const float* __restrict__ normq,
                                                   const float* __restrict__ normp,
                                                   float* __restrict__ fqn,
                                                   float* __restrict__ fpn,
                                                   unsigned short* __restrict__ fqb,
                                                   unsigned short* __restrict__ fpb) {
    const size_t e4 = ((size_t)blockIdx.x * 256 + threadIdx.x) * 4;
    if (e4 >= (size_t)BN * DD) return;
    const int row = (int)(e4 >> 9);
    {
        float4 v = *(const float4*)(ffq + e4);
        float den = __fadd_rn(normq[row], 1e-8f);
        float4 o;
        o.x = __fdiv_rn(v.x, den); o.y = __fdiv_rn(v.y, den);
        o.z = __fdiv_rn(v.z, den); o.w = __fdiv_rn(v.w, den);
        *(float4*)(fqn + e4) = o;
        ushort4 b; b.x = cvt_bf16(o.x); b.y = cvt_bf16(o.y);
        b.z = cvt_bf16(o.z); b.w = cvt_bf16(o.w);
        *(ushort4*)(fqb + e4) = b;
    }
    {
        float4 v = *(const float4*)(ffp + e4);
        float den = __fadd_rn(normp[row], 1e-8f);
        float4 o;
        o.x = __fdiv_rn(v.x, den); o.y = __fdiv_rn(v.y, den);
        o.z = __fdiv_rn(v.z, den); o.w = __fdiv_rn(v.w, den);
        *(float4*)(fpn + e4) = o;
        ushort4 b; b.x = cvt_bf16(o.x); b.y = cvt_bf16(o.y);
        b.z = cvt_bf16(o.z); b.w = cvt_bf16(o.w);
        *(ushort4*)(fpb + e4) = b;
    }
}

// ---------------- Kernel 2 (fast): bf16 MFMA scoring + per-split top-16 -------
// r16/r17/r18 structure (measured optimum: drain loop CK=128, per-chunk A
// frags with opaque offset, bitonic u64 top-16). 426us total at r18.
// r20: XCD-aware remap (T1). Old decode b=bid&7 round-robined batches across
// XCDs -> per-XCD L2 thrash. New: wg=(bid&7)*128+bid/8 (bijective, 1024%8=0)
// gives each XCD one batch b; per-XCD working set fqb[b]+fpb[b] = 4MB = L2.
// Pure block->work permutation: bit-identical output.
// C layout (m89): col=lane&15, row=(lane>>4)*4+reg.
#define CK 128                   // staged K-chunk (bf16 elems); DD/CK = 4
__global__ __launch_bounds__(256, 4) void k_phase1_m(const unsigned short* __restrict__ fqb,
                                                     const unsigned short* __restrict__ fpb,
                                                     unsigned short* __restrict__ cand) {
    __shared__ __align__(16) float simb[QT * SIMP];
    __shared__ __align__(16) unsigned short Bst[64 * CK];   // 16 KB staged B chunk

    const int wg = ((blockIdx.x & 7) << 7) | (blockIdx.x >> 3);   // r20 XCD remap
    const int b  = wg >> 7;
    const int js = (wg >> 5) & 3;
    const int i0 = (wg & 31) * QT;
    const int tid = threadIdx.x;
    const int w = tid >> 6, lane = tid & 63;
    const int n16 = lane & 15, quad = lane >> 4;

    const unsigned short* Aq = fqb + ((size_t)b * NN + i0 + w * 16 + n16) * DD + quad * 8;

    // running top-16 as packed keys, ascending (slot 15 = best). 0 = -inf.
    unsigned long long ktop[16];
#pragma unroll
    for (int r = 0; r < 16; ++r) ktop[r] = 0ull;

    const int qq = tid >> 2;
    const int st = tid & 3;
    const size_t bNN = (size_t)b * NN;

    for (int jt = 0; jt < JRANGE / 64; ++jt) {   // 8 j-tiles of 64
        const int j0g = js * JRANGE + jt * 64;

        f32x4 acc[4];
#pragma unroll
        for (int ct = 0; ct < 4; ++ct) acc[ct] = (f32x4){0.f, 0.f, 0.f, 0.f};

        for (int kc = 0; kc < 4; ++kc) {          // K chunks of 128
            __syncthreads();   // prev chunk's ds_reads / prev tile's sel reads done
            // stage: call l covers LDS rows (w*4+l)*4+quad, block col n16
            // data at LDS block (r, n16) comes from global block (r, n16^(r&15))
#pragma unroll
            for (int l = 0; l < 4; ++l) {
                const int r  = (w * 4 + l) * 4 + quad;
                const int sb = n16 ^ (r & 15);
                const unsigned short* gsrc =
                    fpb + (bNN + j0g + r) * DD + kc * CK + sb * 8;
                gload_lds16(gsrc, &Bst[(w * 4 + l) * 512]);   // 1 KB per call
            }
            // A frags for this chunk only (opaque offset: not hoistable).
            int koff = kc * 128;
            asm volatile("" : "+v"(koff));
            bf16x8 a0 = *(const bf16x8*)(Aq + koff);
            bf16x8 a1 = *(const bf16x8*)(Aq + koff + 32);
            bf16x8 a2 = *(const bf16x8*)(Aq + koff + 64);
            bf16x8 a3 = *(const bf16x8*)(Aq + koff + 96);
            __syncthreads();   // barrier drains vmcnt -> LDS chunk + A frags ready
#pragma unroll
            for (int k4 = 0; k4 < 4; ++k4) {
                const bf16x8 af = (k4 == 0) ? a0 : (k4 == 1) ? a1 : (k4 == 2) ? a2 : a3;
#pragma unroll
                for (int ct = 0; ct < 4; ++ct) {
                    const int r  = ct * 16 + n16;
                    const int cb = (k4 * 4 + quad) ^ (r & 15);
                    bf16x8 bfr = *(const bf16x8*)&Bst[r * CK + cb * 8];
                    acc[ct] = __builtin_amdgcn_mfma_f32_16x16x32_bf16(
                        af, bfr, acc[ct], 0, 0, 0);
                }
            }
        }

        __syncthreads();
#pragma unroll
        for (int ct = 0; ct < 4; ++ct)
#pragma unroll
            for (int r = 0; r < 4; ++r)
                simb[(w * 16 + quad * 4 + r) * SIMP + ct * 16 + n16] = acc[ct][r];
        __syncthreads();

        // ---- r18 selection: branchless bitonic top-16 on packed u64 keys ----
        unsigned long long nk[16];
#pragma unroll
        for (int t4 = 0; t4 < 4; ++t4) {
            const float4 v4 = *(const float4*)&simb[qq * SIMP + st * 16 + t4 * 4];
            const float vv[4] = {v4.x, v4.y, v4.z, v4.w};
#pragma unroll
            for (int u = 0; u < 4; ++u) {
                const float cvf = __fadd_rn(vv[u], 0.0f);     // -0 -> +0
                const unsigned int ub  = __float_as_uint(cvf);
                const unsigned int ord = ub ^ (((unsigned int)((int)ub >> 31)) | 0x80000000u);
                const unsigned int jg  = (unsigned int)(j0g + st * 16 + t4 * 4 + u);
                nk[t4 * 4 + u] = ((unsigned long long)ord << 32)
                               | (unsigned long long)(~jg);
            }
        }
#pragma unroll
        for (int k = 2; k <= 16; k <<= 1) {
#pragma unroll
            for (int j = k >> 1; j > 0; j >>= 1) {
#pragma unroll
                for (int i = 0; i < 16; ++i) {
                    const int l = i ^ j;
                    if (l > i) {
                        const bool up = ((i & k) == 0);
                        const unsigned long long a = nk[i], bq = nk[l];
                        const bool sw = up ? (a > bq) : (a < bq);
                        nk[i] = sw ? bq : a;
                        nk[l] = sw ? a : bq;
                    }
                }
            }
        }
        unsigned long long mg[16];
#pragma unroll
        for (int i = 0; i < 16; ++i) {
            const unsigned long long a = ktop[i], bq = nk[15 - i];
            mg[i] = (a > bq) ? a : bq;
        }
#pragma unroll
        for (int j = 8; j > 0; j >>= 1) {
#pragma unroll
            for (int i = 0; i < 16; ++i) {
                const int l = i ^ j;
                if (l > i) {
                    const unsigned long long a = mg[i], bq = mg[l];
                    const bool sw = a > bq;
                    mg[i] = sw ? bq : a;
                    mg[l] = sw ? a : bq;
                }
            }
        }
#pragma unroll
        for (int i = 0; i < 16; ++i) ktop[i] = mg[i];
    }

    // merge 4 sorted 16-lists (lanes st=0..3 of query qq) -> split top-16.
    __syncthreads();
    int p = 15;
    const size_t base = ((size_t)b * NN + i0 + qq) * MM + (size_t)js * 16;
    for (int m = 0; m < 16; ++m) {
        const unsigned long long myk = (p >= 0) ? ktop[p] : 0ull;
        unsigned long long wk = myk;
        unsigned long long ok;
        ok = __shfl_xor(wk, 1, 4); if (ok > wk) wk = ok;
        ok = __shfl_xor(wk, 2, 4); if (ok > wk) wk = ok;
        if (p >= 0 && myk == wk) --p;
        if (st == 0) cand[base + m] = (unsigned short)(~(unsigned int)wk);
    }
}

// ---------------- Kernel 2 (fallback): r9 fp32 GEMM phase-1 -------------------
#define JTILE 64
#define BK 16
#define LDP 68
__global__ __launch_bounds__(256, 4) void k_phase1_v(const float* __restrict__ ffq,
                                                     const float* __restrict__ ffp,
                                                     const float* __restrict__ rnp32,
                                                     unsigned short* __restrict__ cand) {
    __shared__ __align__(16) float As[BK * LDP];
    __shared__ __align__(16) float Bs[BK * LDP];
    __shared__ __align__(16) float simb[QT * SIMP];

    const int b  = blockIdx.x & 7;
    const int i0 = ((blockIdx.x >> 3) & 31) * QT;
    const int js = blockIdx.x >> 8;
    const int tid = threadIdx.x;
    const int tx = tid & 15, ty = tid >> 4;

    const float* Abase = ffq + ((size_t)b * NN + i0) * DD;
    const float* Bbase = ffp + (size_t)b * NN * DD;

    float tv[16]; int tix[16];
#pragma unroll
    for (int r = 0; r < 16; ++r) { tv[r] = -INFINITY; tix[r] = -1; }

    const int lrow = tid >> 2;
    const int lseg = (tid & 3) * 4;
    const int qq = tid >> 2;
    const int st = tid & 3;

    for (int jt = 0; jt < JRANGE / JTILE; ++jt) {
        const int j0 = js * JRANGE + jt * JTILE;
        float acc[4][4];
#pragma unroll
        for (int r = 0; r < 4; ++r)
#pragma unroll
            for (int c = 0; c < 4; ++c) acc[r][c] = 0.0f;

        for (int kt = 0; kt < DD / BK; ++kt) {
            const int k0 = kt * BK;
            __syncthreads();
            float4 av = *(const float4*)(Abase + (size_t)lrow * DD + k0 + lseg);
            float4 bv = *(const float4*)(Bbase + (size_t)(j0 + lrow) * DD + k0 + lseg);
            As[(lseg + 0) * LDP + lrow] = av.x; As[(lseg + 1) * LDP + lrow] = av.y;
            As[(lseg + 2) * LDP + lrow] = av.z; As[(lseg + 3) * LDP + lrow] = av.w;
            Bs[(lseg + 0) * LDP + lrow] = bv.x; Bs[(lseg + 1) * LDP + lrow] = bv.y;
            Bs[(lseg + 2) * LDP + lrow] = bv.z; Bs[(lseg + 3) * LDP + lrow] = bv.w;
            __syncthreads();
#pragma unroll
            for (int kk = 0; kk < BK; ++kk) {
                const float4 a4 = *(const float4*)&As[kk * LDP + ty * 4];
                const float4 b4 = *(const float4*)&Bs[kk * LDP + tx * 4];
                const float ar[4] = {a4.x, a4.y, a4.z, a4.w};
                const float br[4] = {b4.x, b4.y, b4.z, b4.w};
#pragma unroll
                for (int r = 0; r < 4; ++r)
#pragma unroll
                    for (int c = 0; c < 4; ++c)
                        acc[r][c] = fmaf(ar[r], br[c], acc[r][c]);
            }
        }
        float rp[4];
#pragma unroll
        for (int c = 0; c < 4; ++c) rp[c] = rnp32[b * NN + j0 + tx * 4 + c];
#pragma unroll
        for (int r = 0; r < 4; ++r) {
            float4 v4;
            v4.x = acc[r][0] * rp[0]; v4.y = acc[r][1] * rp[1];
            v4.z = acc[r][2] * rp[2]; v4.w = acc[r][3] * rp[3];
            *(float4*)&simb[(ty * 4 + r) * SIMP + tx * 4] = v4;
        }
        __syncthreads();

#pragma unroll
        for (int t = 0; t < 16; ++t) {
            const int jl = st * 16 + t;
            const float v = simb[qq * SIMP + jl];
            const int jg = j0 + jl;
            if (v > tv[0]) {
#pragma unroll
                for (int r = 0; r < 15; ++r) {
                    const bool up = tv[r + 1] < v;
                    const float nv = up ? tv[r + 1] : ((tv[r] < v) ? v : tv[r]);
                    const int   ni = up ? tix[r + 1] : ((tv[r] < v) ? jg : tix[r]);
                    tv[r] = nv; tix[r] = ni;
                }
                if (tv[15] < v) { tv[15] = v; tix[15] = jg; }
            }
        }
        __syncthreads();
    }

    int p = 15;
    const size_t base = ((size_t)b * NN + i0 + qq) * MM + (size_t)js * 16;
    for (int m = 0; m < 16; ++m) {
        float cv = (p >= 0) ? tv[p] : -INFINITY;
        int   ci = (p >= 0) ? tix[p] : -1;
        float ov; int oi;
        ov = __shfl_xor(cv, 1, 4); oi = __shfl_xor(ci, 1, 4);
        if (ov > cv || (ov == cv && (unsigned)oi < (unsigned)ci)) { cv = ov; ci = oi; }
        ov = __shfl_xor(cv, 2, 4); oi = __shfl_xor(ci, 2, 4);
        if (ov > cv || (ov == cv && (unsigned)oi < (unsigned)ci)) { cv = ov; ci = oi; }
        if (p >= 0 && tv[p] == cv && tix[p] == ci) --p;
        if (st == 0) cand[base + m] = (unsigned short)ci;
    }
}

// ---------------- 3x3 inverse (adjugate) apply ----------------
__device__ inline void inv3_apply(const double* a, double x0, double x1, double x2,
                                  double& y0, double& y1, double& y2) {
    double c00 = a[4]*a[8] - a[5]*a[7];
    double c01 = a[2]*a[7] - a[1]*a[8];
    double c02 = a[1]*a[5] - a[2]*a[4];
    double c10 = a[5]*a[6] - a[3]*a[8];
    double c11 = a[0]*a[8] - a[2]*a[6];
    double c12 = a[2]*a[3] - a[0]*a[5];
    double c20 = a[3]*a[7] - a[4]*a[6];
    double c21 = a[1]*a[6] - a[0]*a[7];
    double c22 = a[0]*a[4] - a[1]*a[3];
    double det = a[0]*c00 + a[1]*c10 + a[2]*c20;
    double id = 1.0 / det;
    y0 = (c00*x0 + c01*x1 + c02*x2) * id;
    y1 = (c10*x0 + c11*x1 + c12*x2) * id;
    y2 = (c20*x0 + c21*x1 + c22*x2) * id;
}

// =============== shared phase-2 body (templated on normalized source) =========
// VERIFIED r8 arithmetic: two ascending-k FMA chains split at d=384, one
// rounded add. Tie: value desc, index asc. DO NOT CHANGE ARITHMETIC.
//
// r10/r12/r16 structure (REVERTED from r19 — per-lane row streaming broke
// coalescing: 64 lanes x 64 rows/instr, 190->425us. LDS staging IS the
// coalescing machinery: 4 lanes x float4 = 64B contiguous per row).
// r20: XCD-aware remap (T1). Old decode b=bid&7 interleaved all 8 batches
// across XCDs. New: wg=(bid&7)*2048+bid/8 (bijective, 16384%8=0) -> each
// XCD owns one batch; candidate-row gathers L2-reuse across neighboring
// queries on the same XCD. Pure permutation: bit-identical output.
#define STG_S 67   // LDS stage row stride (floats)
template <bool PRE>   // PRE: normalized arrays precomputed (fast path)
__device__ inline void phase2_body(
        const float* __restrict__ qin, const float* __restrict__ ffq,
        const float* __restrict__ ffp, const float* __restrict__ R1,
        const float* __restrict__ R2, const int* __restrict__ cent,
        const float* __restrict__ W, const float* __restrict__ bvec,
        const float* __restrict__ normq, const float* __restrict__ normp,
        const float* __restrict__ fqn, const float* __restrict__ fpn,
        const unsigned short* __restrict__ cand, float* __restrict__ out) {
    static_assert(KSPLIT == 384, "chunk split at c=6 assumes KSPLIT==384");
    static_assert(MM * STG_S >= 2 * DD, "meanf/maxf overlay needs 2*DD floats");
    const unsigned int wg = ((blockIdx.x & 7u) << 11) | (blockIdx.x >> 3);  // r20
    const int b = (int)(wg >> 11);
    const int i = (int)(wg & 2047u);
    const int tid = threadIdx.x;
    const size_t qi = (size_t)b * NN + i;

    __shared__ float sfqn[DD];
    __shared__ int cj[MM];
    __shared__ float pden_s[MM];
    __shared__ float sv[MM];
    __shared__ int sel[KK];
    __shared__ __align__(16) float stg[MM * STG_S];   // 16.75 KB stage buffer
    __shared__ float red[3][4];
    // stg is dead after the rescore chains; reuse it for mean/max pooling.
    float* const meanf = stg;
    float* const maxf  = stg + DD;

    if (PRE) {
        for (int d = tid; d < DD; d += 256)
            sfqn[d] = fqn[qi * DD + d];
    } else {
        const float qden = __fadd_rn(normq[qi], 1e-8f);
        for (int d = tid; d < DD; d += 256)
            sfqn[d] = __fdiv_rn(ffq[qi * DD + d], qden);
    }
    if (tid < MM) {
        int j = (int)cand[qi * MM + tid];
        cj[tid] = j;
        if (!PRE) pden_s[tid] = __fadd_rn(normp[(size_t)b * NN + j], 1e-8f);
    }
    __syncthreads();

    // ---- rescore: reg-prefetch pipelined LDS staging, bit-exact chains ----
    const int srow = tid >> 2;          // 0..63: candidate row this thread helps stage
    const int slan = tid & 3;           // 4 lanes x float4 = 64B contiguous per row
    const float* fprow = (PRE ? fpn : ffp) + ((size_t)b * NN + cj[srow]) * DD;
    const float pd = (!PRE) ? pden_s[tid < MM ? tid : 0] : 1.0f;
    float acc1 = 0.0f, acc2 = 0.0f;

    auto stg_write = [&](const float4* P) {
#pragma unroll
        for (int i4 = 0; i4 < 4; ++i4) {
            const int off = srow * STG_S + i4 * 16 + slan * 4;
            stg[off + 0] = P[i4].x; stg[off + 1] = P[i4].y;
            stg[off + 2] = P[i4].z; stg[off + 3] = P[i4].w;
        }
    };
    auto ld_chunk = [&](float4* P, int c) {
#pragma unroll
        for (int i4 = 0; i4 < 4; ++i4)
            P[i4] = *(const float4*)(fprow + c * 64 + i4 * 16 + slan * 4);
    };
    auto chain = [&](int c, float& acc) {
        const int d0 = c * 64;
        const float* s = stg + tid * STG_S;
        if (PRE) {
#pragma unroll
            for (int k = 0; k < 64; ++k)
                acc = fmaf(sfqn[d0 + k], s[k], acc);
        } else {
#pragma unroll
            for (int k = 0; k < 64; ++k)
                acc = fmaf(sfqn[d0 + k], __fdiv_rn(s[k], pd), acc);
        }
    };

    float4 pA[4], pB[4];
    ld_chunk(pA, 0);
#pragma unroll
    for (int ch = 0; ch < 4; ++ch) {
        // ---- even chunk c0 = 2*ch: stg <- pA, prefetch c0+1 -> pB ----
        {
            const int c0 = 2 * ch;
            stg_write(pA);
            ld_chunk(pB, c0 + 1);               // always valid (c0+1 <= 7)
            __syncthreads();
            if (tid < MM) chain(c0, (c0 < 6) ? acc1 : acc2);
            __syncthreads();                     // chain reads done before overwrite
        }
        // ---- odd chunk c1 = 2*ch+1: stg <- pB, prefetch c1+1 -> pA ----
        {
            const int c1 = 2 * ch + 1;
            stg_write(pB);
            if (ch < 3) ld_chunk(pA, c1 + 1);    // constant-folded under unroll
            __syncthreads();
            if (tid < MM) chain(c1, (c1 < 6) ? acc1 : acc2);
            __syncthreads();
        }
    }
    if (tid < MM) sv[tid] = __fadd_rn(acc1, acc2);
    __syncthreads();

    if (tid < MM) {
        const float v = sv[tid]; const int jj = cj[tid];
        int rank = 0;
        for (int t = 0; t < MM; ++t) {
            const float vt = sv[t]; const int jo = cj[t];
            rank += (vt > v) || (vt == v && jo < jj);
        }
        if (rank < KK) {
            sel[rank] = jj;
            out[(size_t)OUT3 + qi * KK + rank] = (float)jj;
        }
    }
    __syncthreads();

    for (int d = tid; d < DD; d += 256) {
        float sum = 0.0f, mx = -INFINITY;
#pragma unroll
        for (int k = 0; k < KK; ++k) {
            float v = ffp[((size_t)b * NN + sel[k]) * DD + d];
            sum += v; mx = fmaxf(mx, v);
        }
        meanf[d] = sum * (1.0f / 16.0f);
        maxf[d]  = mx;
    }
    __syncthreads();

    float a0 = 0.f, a1 = 0.f, a2 = 0.f;
    for (int d = tid; d < DD; d += 256) {
        const float x = ffq[qi * DD + d], m = meanf[d], mx = maxf[d];
        a0 = fmaf(W[d],        x, a0); a0 = fmaf(W[512 + d],        m, a0); a0 = fmaf(W[1024 + d],        mx, a0);
        a1 = fmaf(W[1536 + d], x, a1); a1 = fmaf(W[1536 + 512 + d], m, a1); a1 = fmaf(W[1536 + 1024 + d], mx, a1);
        a2 = fmaf(W[3072 + d], x, a2); a2 = fmaf(W[3072 + 512 + d], m, a2); a2 = fmaf(W[3072 + 1024 + d], mx, a2);
    }
#pragma unroll
    for (int off = 32; off > 0; off >>= 1) {
        a0 += __shfl_down(a0, off, 64);
        a1 += __shfl_down(a1, off, 64);
        a2 += __shfl_down(a2, off, 64);
    }
    const int lane = tid & 63, wid = tid >> 6;
    if (lane == 0) { red[0][wid] = a0; red[1][wid] = a1; red[2][wid] = a2; }
    __syncthreads();

    if (tid == 0) {
        double v0 = (double)bvec[0] + red[0][0] + red[0][1] + red[0][2] + red[0][3];
        double v1 = (double)bvec[1] + red[1][0] + red[1][1] + red[1][2] + red[1][3];
        double v2 = (double)bvec[2] + red[2][0] + red[2][1] + red[2][2] + red[2][3];
        double r1[9], r2[9];
#pragma unroll
        for (int t = 0; t < 9; ++t) { r1[t] = R1[qi * 9 + t]; r2[t] = R2[qi * 9 + t]; }
        double u0, u1, u2, w0, w1, w2;
        inv3_apply(r1, v0, v1, v2, u0, u1, u2);
        inv3_apply(r2, u0, u1, u2, w0, w1, w2);
        const float mask = (cent[qi] >= NN) ? 1.0f : 0.0f;
        const float q0 = qin[qi * 3 + 0], q1 = qin[qi * 3 + 1], q2 = qin[qi * 3 + 2];
        out[qi * 3 + 0] = q0; out[qi * 3 + 1] = q1; out[qi * 3 + 2] = q2;
        const float o0 = q0 + (float)w0 * mask;
        const float o1 = q1 + (float)w1 * mask;
        const float o2 = q2 + (float)w2 * mask;
        out[OUT1 + qi * 3 + 0] = o0; out[OUT1 + qi * 3 + 1] = o1; out[OUT1 + qi * 3 + 2] = o2;
        out[OUT2 + qi * 3 + 0] = o0; out[OUT2 + qi * 3 + 1] = o1; out[OUT2 + qi * 3 + 2] = o2;
    }
}

__global__ __launch_bounds__(256, 8) void k_phase2_f(
        const float* qin, const float* ffq, const float* ffp, const float* R1,
        const float* R2, const int* cent, const float* W, const float* bvec,
        const float* fqn, const float* fpn, const unsigned short* cand, float* out) {
    phase2_body<true>(qin, ffq, ffp, R1, R2, cent, W, bvec,
                      nullptr, nullptr, fqn, fpn, cand, out);
}

__global__ __launch_bounds__(256, 8) void k_phase2_v(
        const float* qin, const float* ffq, const float* ffp, const float* R1,
        const float* R2, const int* cent, const float* W, const float* bvec,
        const float* normq, const float* normp, const unsigned short* cand, float* out) {
    phase2_body<false>(qin, ffq, ffp, R1, R2, cent, W, bvec,
                       normq, normp, nullptr, nullptr, cand, out);
}

extern "C" void kernel_launch(void* const* d_in, const int* in_sizes, int n_in,
                              void* d_out, int out_size, void* d_ws, size_t ws_size,
                              hipStream_t stream) {
    (void)in_sizes; (void)n_in; (void)out_size;
    const float* q   = (const float*)d_in[1];
    const float* ffp = (const float*)d_in[2];
    const float* ffq = (const float*)d_in[3];
    const float* R1  = (const float*)d_in[4];
    const float* R2  = (const float*)d_in[5];
    const int*   ct  = (const int*)d_in[6];
    const float* W   = (const float*)d_in[7];
    const float* bb  = (const float*)d_in[8];
    float* out = (float*)d_out;

    float* normq = (float*)d_ws;                               // BN
    float* normp = normq + BN;                                 // BN
    float* rnp32 = normp + BN;                                 // BN
    unsigned short* cand = (unsigned short*)(rnp32 + BN);      // BN*MM u16
    float* fqn = (float*)(cand + (size_t)BN * MM);             // BN*DD
    float* fpn = fqn + (size_t)BN * DD;                        // BN*DD
    unsigned short* fqb = (unsigned short*)(fpn + (size_t)BN * DD);  // BN*DD u16
    unsigned short* fpb = fqb + (size_t)BN * DD;               // BN*DD u16

    const size_t need = (size_t)BN * (35 * 4 + 2 * DD * 4 + 2 * DD * 2);

    k_norm_np<<<dim3((2 * BN) / 32), dim3(256), 0, stream>>>(ffq, ffp, normq, normp, rnp32);

    if (ws_size >= need) {
        k_normalize<<<dim3((BN * DD) / 1024), dim3(256), 0, stream>>>(
            ffq, ffp, normq, normp, fqn, fpn, fqb, fpb);
        k_phase1_m<<<dim3(BB * (NN / QT) * JSPLIT), dim3(256), 0, stream>>>(fqb, fpb, cand);
        k_phase2_f<<<dim3(BB * NN), dim3(256), 0, stream>>>(q, ffq, ffp, R1, R2, ct, W, bb,
                                                            fqn, fpn, cand, out);
    } else {
        k_phase1_v<<<dim3(BB * (NN / QT) * JSPLIT), dim3(256), 0, stream>>>(ffq, ffp, rnp32, cand);
        k_phase2_v<<<dim3(BB * NN), dim3(256), 0, stream>>>(q, ffq, ffp, R1, R2, ct, W, bb,
                                                            normq, normp, cand, out);
    }
}

// Round 15
// 426.749 us; speedup vs baseline: 1.5738x; 1.0099x over previous
//
#include <hip/hip_runtime.h>
#include <math.h>

#define BB 8
#define NN 2048
#define DD 512
#define KK 16
#define BN (BB*NN)

#define QT 64
#define JSPLIT 4
#define JRANGE (NN/JSPLIT)      // 512 candidates per block
#define MM (16*JSPLIT)          // 64 candidates per query into phase-2
#define SIMP 68                 // simb row stride (floats)

#define KSPLIT 384              // OpenBLAS SGEMM_DEFAULT_Q (ZEN) — DO NOT CHANGE

#define OUT1 (BN*3)
#define OUT2 (2*BN*3)
#define OUT3 (3*BN*3)

typedef __attribute__((ext_vector_type(8))) short bf16x8;
typedef __attribute__((ext_vector_type(4))) float f32x4;

__device__ inline unsigned short cvt_bf16(float f) {   // RNE, finite inputs
    unsigned int u = __float_as_uint(f);
    return (unsigned short)((u + 0x7fffu + ((u >> 16) & 1u)) >> 16);
}

// async global->LDS, 16B per lane; lds must be wave-uniform base (HW adds lane*16)
__device__ inline void gload_lds16(const unsigned short* g, unsigned short* lds) {
    __builtin_amdgcn_global_load_lds((const __attribute__((address_space(1))) void*)g,
                                     (__attribute__((address_space(3))) void*)lds,
                                     16, 0, 0);
}

// ---------------- Kernel 1: numpy-bit-exact f32 row norms (scalar-8 base) -----
// VERIFIED r8. DO NOT CHANGE ARITHMETIC.
__global__ __launch_bounds__(256) void k_norm_np(const float* __restrict__ ffq,
                                                 const float* __restrict__ ffp,
                                                 float* __restrict__ normq,
                                                 float* __restrict__ normp,
                                                 float* __restrict__ rnp32) {
    const int row = blockIdx.x * 32 + (threadIdx.x >> 3);
    const int j   = threadIdx.x & 7;
    const bool isQ = row < BN;
    const int r = isQ ? row : row - BN;
    const float* x = (isQ ? ffq : ffp) + (size_t)r * DD;

    float B[4];
#pragma unroll
    for (int t = 0; t < 4; ++t) {
        const float* xb = x + t * 128;
        float e = xb[j];
        float rj = __fmul_rn(e, e);
#pragma unroll
        for (int i = 1; i < 16; ++i) {
            float v = xb[8 * i + j];
            rj = __fadd_rn(rj, __fmul_rn(v, v));
        }
        float s = __fadd_rn(rj, __shfl_xor(rj, 1, 8));
        float u = __fadd_rn(s,  __shfl_xor(s,  2, 8));
        float w = __fadd_rn(u,  __shfl_xor(u,  4, 8));
        B[t] = w;
    }
    if (j == 0) {
        float norm2 = __fadd_rn(__fadd_rn(B[0], B[1]), __fadd_rn(B[2], B[3]));
        float nrm = __fsqrt_rn(norm2);
        if (isQ) { normq[r] = nrm; }
        else {
            normp[r] = nrm;
            rnp32[r] = 1.0f / __fadd_rn(nrm, 1e-8f);
        }
    }
}

// ---------------- Kernel 1b: normalized f32 (exact bits) + bf16 copies --------
__global__ __launch_bounds__(256) void k_normalize(const float* __restrict__ ffq,
                                                   const float* __restrict__ ffp,
                                                   const float* __restrict__ normq,
                                                   const float* __restrict__ normp,
                                                   float* __restrict__ fqn,
                                                   float* __restrict__ fpn,
                                                   unsigned short* __restrict__ fqb,
                                                   unsigned short* __restrict__ fpb) {
    const size_t e4 = ((size_t)blockIdx.x * 256 + threadIdx.x) * 4;
    if (e4 >= (size_t)BN * DD) return;
    const int row = (int)(e4 >> 9);
    {
        float4 v = *(const float4*)(ffq + e4);
        float den = __fadd_rn(normq[row], 1e-8f);
        float4 o;
        o.x = __fdiv_rn(v.x, den); o.y = __fdiv_rn(v.y, den);
        o.z = __fdiv_rn(v.z, den); o.w = __fdiv_rn(v.w, den);
        *(float4*)(fqn + e4) = o;
        ushort4 b; b.x = cvt_bf16(o.x); b.y = cvt_bf16(o.y);
        b.z = cvt_bf16(o.z); b.w = cvt_bf16(o.w);
        *(ushort4*)(fqb + e4) = b;
    }
    {
        float4 v = *(const float4*)(ffp + e4);
        float den = __fadd_rn(normp[row], 1e-8f);
        float4 o;
        o.x = __fdiv_rn(v.x, den); o.y = __fdiv_rn(v.y, den);
        o.z = __fdiv_rn(v.z, den); o.w = __fdiv_rn(v.w, den);
        *(float4*)(fpn + e4) = o;
        ushort4 b; b.x = cvt_bf16(o.x); b.y = cvt_bf16(o.y);
        b.z = cvt_bf16(o.z); b.w = cvt_bf16(o.w);
        *(ushort4*)(fpb + e4) = b;
    }
}

// ---------------- Kernel 2 (fast): bf16 MFMA scoring + per-split top-16 -------
// r16/r17/r18 structure (measured optimum: drain loop CK=128, per-chunk A
// frags with opaque offset, bitonic u64 top-16). 426us total at r18.
// r21: phase-1 XCD remap REVERTED (r20 A/B: phase-2 improved 190->176 but
// total rose 426->431 => phase-1 lost ~19us. Mechanism: remap pinned each
// XCD to fqb[b]+fpb[b]=4MB = 100% of its L2 -> capacity thrash; phase-1's
// FETCH was only 17MB — it never had a locality problem). Original decode
// restored here; phase-2 keeps its measured-good remap.
// C layout (m89): col=lane&15, row=(lane>>4)*4+reg.
#define CK 128                   // staged K-chunk (bf16 elems); DD/CK = 4
__global__ __launch_bounds__(256, 4) void k_phase1_m(const unsigned short* __restrict__ fqb,
                                                     const unsigned short* __restrict__ fpb,
                                                     unsigned short* __restrict__ cand) {
    __shared__ __align__(16) float simb[QT * SIMP];
    __shared__ __align__(16) unsigned short Bst[64 * CK];   // 16 KB staged B chunk

    const int b  = blockIdx.x & 7;
    const int i0 = ((blockIdx.x >> 3) & 31) * QT;
    const int js = blockIdx.x >> 8;
    const int tid = threadIdx.x;
    const int w = tid >> 6, lane = tid & 63;
    const int n16 = lane & 15, quad = lane >> 4;

    const unsigned short* Aq = fqb + ((size_t)b * NN + i0 + w * 16 + n16) * DD + quad * 8;

    // running top-16 as packed keys, ascending (slot 15 = best). 0 = -inf.
    unsigned long long ktop[16];
#pragma unroll
    for (int r = 0; r < 16; ++r) ktop[r] = 0ull;

    const int qq = tid >> 2;
    const int st = tid & 3;
    const size_t bNN = (size_t)b * NN;

    for (int jt = 0; jt < JRANGE / 64; ++jt) {   // 8 j-tiles of 64
        const int j0g = js * JRANGE + jt * 64;

        f32x4 acc[4];
#pragma unroll
        for (int ct = 0; ct < 4; ++ct) acc[ct] = (f32x4){0.f, 0.f, 0.f, 0.f};

        for (int kc = 0; kc < 4; ++kc) {          // K chunks of 128
            __syncthreads();   // prev chunk's ds_reads / prev tile's sel reads done
            // stage: call l covers LDS rows (w*4+l)*4+quad, block col n16
            // data at LDS block (r, n16) comes from global block (r, n16^(r&15))
#pragma unroll
            for (int l = 0; l < 4; ++l) {
                const int r  = (w * 4 + l) * 4 + quad;
                const int sb = n16 ^ (r & 15);
                const unsigned short* gsrc =
                    fpb + (bNN + j0g + r) * DD + kc * CK + sb * 8;
                gload_lds16(gsrc, &Bst[(w * 4 + l) * 512]);   // 1 KB per call
            }
            // A frags for this chunk only (opaque offset: not hoistable).
            int koff = kc * 128;
            asm volatile("" : "+v"(koff));
            bf16x8 a0 = *(const bf16x8*)(Aq + koff);
            bf16x8 a1 = *(const bf16x8*)(Aq + koff + 32);
            bf16x8 a2 = *(const bf16x8*)(Aq + koff + 64);
            bf16x8 a3 = *(const bf16x8*)(Aq + koff + 96);
            __syncthreads();   // barrier drains vmcnt -> LDS chunk + A frags ready
#pragma unroll
            for (int k4 = 0; k4 < 4; ++k4) {
                const bf16x8 af = (k4 == 0) ? a0 : (k4 == 1) ? a1 : (k4 == 2) ? a2 : a3;
#pragma unroll
                for (int ct = 0; ct < 4; ++ct) {
                    const int r  = ct * 16 + n16;
                    const int cb = (k4 * 4 + quad) ^ (r & 15);
                    bf16x8 bfr = *(const bf16x8*)&Bst[r * CK + cb * 8];
                    acc[ct] = __builtin_amdgcn_mfma_f32_16x16x32_bf16(
                        af, bfr, acc[ct], 0, 0, 0);
                }
            }
        }

        __syncthreads();
#pragma unroll
        for (int ct = 0; ct < 4; ++ct)
#pragma unroll
            for (int r = 0; r < 4; ++r)
                simb[(w * 16 + quad * 4 + r) * SIMP + ct * 16 + n16] = acc[ct][r];
        __syncthreads();

        // ---- r18 selection: branchless bitonic top-16 on packed u64 keys ----
        unsigned long long nk[16];
#pragma unroll
        for (int t4 = 0; t4 < 4; ++t4) {
            const float4 v4 = *(const float4*)&simb[qq * SIMP + st * 16 + t4 * 4];
            const float vv[4] = {v4.x, v4.y, v4.z, v4.w};
#pragma unroll
            for (int u = 0; u < 4; ++u) {
                const float cvf = __fadd_rn(vv[u], 0.0f);     // -0 -> +0
                const unsigned int ub  = __float_as_uint(cvf);
                const unsigned int ord = ub ^ (((unsigned int)((int)ub >> 31)) | 0x80000000u);
                const unsigned int jg  = (unsigned int)(j0g + st * 16 + t4 * 4 + u);
                nk[t4 * 4 + u] = ((unsigned long long)ord << 32)
                               | (unsigned long long)(~jg);
            }
        }
#pragma unroll
        for (int k = 2; k <= 16; k <<= 1) {
#pragma unroll
            for (int j = k >> 1; j > 0; j >>= 1) {
#pragma unroll
                for (int i = 0; i < 16; ++i) {
                    const int l = i ^ j;
                    if (l > i) {
                        const bool up = ((i & k) == 0);
                        const unsigned long long a = nk[i], bq = nk[l];
                        const bool sw = up ? (a > bq) : (a < bq);
                        nk[i] = sw ? bq : a;
                        nk[l] = sw ? a : bq;
                    }
                }
            }
        }
        unsigned long long mg[16];
#pragma unroll
        for (int i = 0; i < 16; ++i) {
            const unsigned long long a = ktop[i], bq = nk[15 - i];
            mg[i] = (a > bq) ? a : bq;
        }
#pragma unroll
        for (int j = 8; j > 0; j >>= 1) {
#pragma unroll
            for (int i = 0; i < 16; ++i) {
                const int l = i ^ j;
                if (l > i) {
                    const unsigned long long a = mg[i], bq = mg[l];
                    const bool sw = a > bq;
                    mg[i] = sw ? bq : a;
                    mg[l] = sw ? a : bq;
                }
            }
        }
#pragma unroll
        for (int i = 0; i < 16; ++i) ktop[i] = mg[i];
    }

    // merge 4 sorted 16-lists (lanes st=0..3 of query qq) -> split top-16.
    __syncthreads();
    int p = 15;
    const size_t base = ((size_t)b * NN + i0 + qq) * MM + (size_t)js * 16;
    for (int m = 0; m < 16; ++m) {
        const unsigned long long myk = (p >= 0) ? ktop[p] : 0ull;
        unsigned long long wk = myk;
        unsigned long long ok;
        ok = __shfl_xor(wk, 1, 4); if (ok > wk) wk = ok;
        ok = __shfl_xor(wk, 2, 4); if (ok > wk) wk = ok;
        if (p >= 0 && myk == wk) --p;
        if (st == 0) cand[base + m] = (unsigned short)(~(unsigned int)wk);
    }
}

// ---------------- Kernel 2 (fallback): r9 fp32 GEMM phase-1 -------------------
#define JTILE 64
#define BK 16
#define LDP 68
__global__ __launch_bounds__(256, 4) void k_phase1_v(const float* __restrict__ ffq,
                                                     const float* __restrict__ ffp,
                                                     const float* __restrict__ rnp32,
                                                     unsigned short* __restrict__ cand) {
    __shared__ __align__(16) float As[BK * LDP];
    __shared__ __align__(16) float Bs[BK * LDP];
    __shared__ __align__(16) float simb[QT * SIMP];

    const int b  = blockIdx.x & 7;
    const int i0 = ((blockIdx.x >> 3) & 31) * QT;
    const int js = blockIdx.x >> 8;
    const int tid = threadIdx.x;
    const int tx = tid & 15, ty = tid >> 4;

    const float* Abase = ffq + ((size_t)b * NN + i0) * DD;
    const float* Bbase = ffp + (size_t)b * NN * DD;

    float tv[16]; int tix[16];
#pragma unroll
    for (int r = 0; r < 16; ++r) { tv[r] = -INFINITY; tix[r] = -1; }

    const int lrow = tid >> 2;
    const int lseg = (tid & 3) * 4;
    const int qq = tid >> 2;
    const int st = tid & 3;

    for (int jt = 0; jt < JRANGE / JTILE; ++jt) {
        const int j0 = js * JRANGE + jt * JTILE;
        float acc[4][4];
#pragma unroll
        for (int r = 0; r < 4; ++r)
#pragma unroll
            for (int c = 0; c < 4; ++c) acc[r][c] = 0.0f;

        for (int kt = 0; kt < DD / BK; ++kt) {
            const int k0 = kt * BK;
            __syncthreads();
            float4 av = *(const float4*)(Abase + (size_t)lrow * DD + k0 + lseg);
            float4 bv = *(const float4*)(Bbase + (size_t)(j0 + lrow) * DD + k0 + lseg);
            As[(lseg + 0) * LDP + lrow] = av.x; As[(lseg + 1) * LDP + lrow] = av.y;
            As[(lseg + 2) * LDP + lrow] = av.z; As[(lseg + 3) * LDP + lrow] = av.w;
            Bs[(lseg + 0) * LDP + lrow] = bv.x; Bs[(lseg + 1) * LDP + lrow] = bv.y;
            Bs[(lseg + 2) * LDP + lrow] = bv.z; Bs[(lseg + 3) * LDP + lrow] = bv.w;
            __syncthreads();
#pragma unroll
            for (int kk = 0; kk < BK; ++kk) {
                const float4 a4 = *(const float4*)&As[kk * LDP + ty * 4];
                const float4 b4 = *(const float4*)&Bs[kk * LDP + tx * 4];
                const float ar[4] = {a4.x, a4.y, a4.z, a4.w};
                const float br[4] = {b4.x, b4.y, b4.z, b4.w};
#pragma unroll
                for (int r = 0; r < 4; ++r)
#pragma unroll
                    for (int c = 0; c < 4; ++c)
                        acc[r][c] = fmaf(ar[r], br[c], acc[r][c]);
            }
        }
        float rp[4];
#pragma unroll
        for (int c = 0; c < 4; ++c) rp[c] = rnp32[b * NN + j0 + tx * 4 + c];
#pragma unroll
        for (int r = 0; r < 4; ++r) {
            float4 v4;
            v4.x = acc[r][0] * rp[0]; v4.y = acc[r][1] * rp[1];
            v4.z = acc[r][2] * rp[2]; v4.w = acc[r][3] * rp[3];
            *(float4*)&simb[(ty * 4 + r) * SIMP + tx * 4] = v4;
        }
        __syncthreads();

#pragma unroll
        for (int t = 0; t < 16; ++t) {
            const int jl = st * 16 + t;
            const float v = simb[qq * SIMP + jl];
            const int jg = j0 + jl;
            if (v > tv[0]) {
#pragma unroll
                for (int r = 0; r < 15; ++r) {
                    const bool up = tv[r + 1] < v;
                    const float nv = up ? tv[r + 1] : ((tv[r] < v) ? v : tv[r]);
                    const int   ni = up ? tix[r + 1] : ((tv[r] < v) ? jg : tix[r]);
                    tv[r] = nv; tix[r] = ni;
                }
                if (tv[15] < v) { tv[15] = v; tix[15] = jg; }
            }
        }
        __syncthreads();
    }

    int p = 15;
    const size_t base = ((size_t)b * NN + i0 + qq) * MM + (size_t)js * 16;
    for (int m = 0; m < 16; ++m) {
        float cv = (p >= 0) ? tv[p] : -INFINITY;
        int   ci = (p >= 0) ? tix[p] : -1;
        float ov; int oi;
        ov = __shfl_xor(cv, 1, 4); oi = __shfl_xor(ci, 1, 4);
        if (ov > cv || (ov == cv && (unsigned)oi < (unsigned)ci)) { cv = ov; ci = oi; }
        ov = __shfl_xor(cv, 2, 4); oi = __shfl_xor(ci, 2, 4);
        if (ov > cv || (ov == cv && (unsigned)oi < (unsigned)ci)) { cv = ov; ci = oi; }
        if (p >= 0 && tv[p] == cv && tix[p] == ci) --p;
        if (st == 0) cand[base + m] = (unsigned short)ci;
    }
}

// ---------------- 3x3 inverse (adjugate) apply ----------------
__device__ inline void inv3_apply(const double* a, double x0, double x1, double x2,
                                  double& y0, double& y1, double& y2) {
    double c00 = a[4]*a[8] - a[5]*a[7];
    double c01 = a[2]*a[7] - a[1]*a[8];
    double c02 = a[1]*a[5] - a[2]*a[4];
    double c10 = a[5]*a[6] - a[3]*a[8];
    double c11 = a[0]*a[8] - a[2]*a[6];
    double c12 = a[2]*a[3] - a[0]*a[5];
    double c20 = a[3]*a[7] - a[4]*a[6];
    double c21 = a[1]*a[6] - a[0]*a[7];
    double c22 = a[0]*a[4] - a[1]*a[3];
    double det = a[0]*c00 + a[1]*c10 + a[2]*c20;
    double id = 1.0 / det;
    y0 = (c00*x0 + c01*x1 + c02*x2) * id;
    y1 = (c10*x0 + c11*x1 + c12*x2) * id;
    y2 = (c20*x0 + c21*x1 + c22*x2) * id;
}

// =============== shared phase-2 body (templated on normalized source) =========
// VERIFIED r8 arithmetic: two ascending-k FMA chains split at d=384, one
// rounded add. Tie: value desc, index asc. DO NOT CHANGE ARITHMETIC.
//
// r10/r12/r16 structure (r19 per-lane streaming reverted: LDS staging IS the
// coalescing machinery — 4 lanes x float4 = 64B contiguous per row).
// r20: XCD-aware remap (T1), KEPT here (measured 190->176us, +0.4TB/s HBM).
// wg=(bid&7)*2048+bid/8 (bijective, 16384%8=0) -> each XCD owns one batch;
// candidate-row gathers L2-reuse on the same XCD. Pure permutation.
#define STG_S 67   // LDS stage row stride (floats)
template <bool PRE>   // PRE: normalized arrays precomputed (fast path)
__device__ inline void phase2_body(
        const float* __restrict__ qin, const float* __restrict__ ffq,
        const float* __restrict__ ffp, const float* __restrict__ R1,
        const float* __restrict__ R2, const int* __restrict__ cent,
        const float* __restrict__ W, const float* __restrict__ bvec,
        const float* __restrict__ normq, const float* __restrict__ normp,
        const float* __restrict__ fqn, const float* __restrict__ fpn,
        const unsigned short* __restrict__ cand, float* __restrict__ out) {
    static_assert(KSPLIT == 384, "chunk split at c=6 assumes KSPLIT==384");
    static_assert(MM * STG_S >= 2 * DD, "meanf/maxf overlay needs 2*DD floats");
    const unsigned int wg = ((blockIdx.x & 7u) << 11) | (blockIdx.x >> 3);  // r20
    const int b = (int)(wg >> 11);
    const int i = (int)(wg & 2047u);
    const int tid = threadIdx.x;
    const size_t qi = (size_t)b * NN + i;

    __shared__ float sfqn[DD];
    __shared__ int cj[MM];
    __shared__ float pden_s[MM];
    __shared__ float sv[MM];
    __shared__ int sel[KK];
    __shared__ __align__(16) float stg[MM * STG_S];   // 16.75 KB stage buffer
    __shared__ float red[3][4];
    // stg is dead after the rescore chains; reuse it for mean/max pooling.
    float* const meanf = stg;
    float* const maxf  = stg + DD;

    if (PRE) {
        for (int d = tid; d < DD; d += 256)
            sfqn[d] = fqn[qi * DD + d];
    } else {
        const float qden = __fadd_rn(normq[qi], 1e-8f);
        for (int d = tid; d < DD; d += 256)
            sfqn[d] = __fdiv_rn(ffq[qi * DD + d], qden);
    }
    if (tid < MM) {
        int j = (int)cand[qi * MM + tid];
        cj[tid] = j;
        if (!PRE) pden_s[tid] = __fadd_rn(normp[(size_t)b * NN + j], 1e-8f);
    }
    __syncthreads();

    // ---- rescore: reg-prefetch pipelined LDS staging, bit-exact chains ----
    const int srow = tid >> 2;          // 0..63: candidate row this thread helps stage
    const int slan = tid & 3;           // 4 lanes x float4 = 64B contiguous per row
    const float* fprow = (PRE ? fpn : ffp) + ((size_t)b * NN + cj[srow]) * DD;
    const float pd = (!PRE) ? pden_s[tid < MM ? tid : 0] : 1.0f;
    float acc1 = 0.0f, acc2 = 0.0f;

    auto stg_write = [&](const float4* P) {
#pragma unroll
        for (int i4 = 0; i4 < 4; ++i4) {
            const int off = srow * STG_S + i4 * 16 + slan * 4;
            stg[off + 0] = P[i4].x; stg[off + 1] = P[i4].y;
            stg[off + 2] = P[i4].z; stg[off + 3] = P[i4].w;
        }
    };
    auto ld_chunk = [&](float4* P, int c) {
#pragma unroll
        for (int i4 = 0; i4 < 4; ++i4)
            P[i4] = *(const float4*)(fprow + c * 64 + i4 * 16 + slan * 4);
    };
    auto chain = [&](int c, float& acc) {
        const int d0 = c * 64;
        const float* s = stg + tid * STG_S;
        if (PRE) {
#pragma unroll
            for (int k = 0; k < 64; ++k)
                acc = fmaf(sfqn[d0 + k], s[k], acc);
        } else {
#pragma unroll
            for (int k = 0; k < 64; ++k)
                acc = fmaf(sfqn[d0 + k], __fdiv_rn(s[k], pd), acc);
        }
    };

    float4 pA[4], pB[4];
    ld_chunk(pA, 0);
#pragma unroll
    for (int ch = 0; ch < 4; ++ch) {
        // ---- even chunk c0 = 2*ch: stg <- pA, prefetch c0+1 -> pB ----
        {
            const int c0 = 2 * ch;
            stg_write(pA);
            ld_chunk(pB, c0 + 1);               // always valid (c0+1 <= 7)
            __syncthreads();
            if (tid < MM) chain(c0, (c0 < 6) ? acc1 : acc2);
            __syncthreads();                     // chain reads done before overwrite
        }
        // ---- odd chunk c1 = 2*ch+1: stg <- pB, prefetch c1+1 -> pA ----
        {
            const int c1 = 2 * ch + 1;
            stg_write(pB);
            if (ch < 3) ld_chunk(pA, c1 + 1);    // constant-folded under unroll
            __syncthreads();
            if (tid < MM) chain(c1, (c1 < 6) ? acc1 : acc2);
            __syncthreads();
        }
    }
    if (tid < MM) sv[tid] = __fadd_rn(acc1, acc2);
    __syncthreads();

    if (tid < MM) {
        const float v = sv[tid]; const int jj = cj[tid];
        int rank = 0;
        for (int t = 0; t < MM; ++t) {
            const float vt = sv[t]; const int jo = cj[t];
            rank += (vt > v) || (vt == v && jo < jj);
        }
        if (rank < KK) {
            sel[rank] = jj;
            out[(size_t)OUT3 + qi * KK + rank] = (float)jj;
        }
    }
    __syncthreads();

    for (int d = tid; d < DD; d += 256) {
        float sum = 0.0f, mx = -INFINITY;
#pragma unroll
        for (int k = 0; k < KK; ++k) {
            float v = ffp[((size_t)b * NN + sel[k]) * DD + d];
            sum += v; mx = fmaxf(mx, v);
        }
        meanf[d] = sum * (1.0f / 16.0f);
        maxf[d]  = mx;
    }
    __syncthreads();

    float a0 = 0.f, a1 = 0.f, a2 = 0.f;
    for (int d = tid; d < DD; d += 256) {
        const float x = ffq[qi * DD + d], m = meanf[d], mx = maxf[d];
        a0 = fmaf(W[d],        x, a0); a0 = fmaf(W[512 + d],        m, a0); a0 = fmaf(W[1024 + d],        mx, a0);
        a1 = fmaf(W[1536 + d], x, a1); a1 = fmaf(W[1536 + 512 + d], m, a1); a1 = fmaf(W[1536 + 1024 + d], mx, a1);
        a2 = fmaf(W[3072 + d], x, a2); a2 = fmaf(W[3072 + 512 + d], m, a2); a2 = fmaf(W[3072 + 1024 + d], mx, a2);
    }
#pragma unroll
    for (int off = 32; off > 0; off >>= 1) {
        a0 += __shfl_down(a0, off, 64);
        a1 += __shfl_down(a1, off, 64);
        a2 += __shfl_down(a2, off, 64);
    }
    const int lane = tid & 63, wid = tid >> 6;
    if (lane == 0) { red[0][wid] = a0; red[1][wid] = a1; red[2][wid] = a2; }
    __syncthreads();

    if (tid == 0) {
        double v0 = (double)bvec[0] + red[0][0] + red[0][1] + red[0][2] + red[0][3];
        double v1 = (double)bvec[1] + red[1][0] + red[1][1] + red[1][2] + red[1][3];
        double v2 = (double)bvec[2] + red[2][0] + red[2][1] + red[2][2] + red[2][3];
        double r1[9], r2[9];
#pragma unroll
        for (int t = 0; t < 9; ++t) { r1[t] = R1[qi * 9 + t]; r2[t] = R2[qi * 9 + t]; }
        double u0, u1, u2, w0, w1, w2;
        inv3_apply(r1, v0, v1, v2, u0, u1, u2);
        inv3_apply(r2, u0, u1, u2, w0, w1, w2);
        const float mask = (cent[qi] >= NN) ? 1.0f : 0.0f;
        const float q0 = qin[qi * 3 + 0], q1 = qin[qi * 3 + 1], q2 = qin[qi * 3 + 2];
        out[qi * 3 + 0] = q0; out[qi * 3 + 1] = q1; out[qi * 3 + 2] = q2;
        const float o0 = q0 + (float)w0 * mask;
        const float o1 = q1 + (float)w1 * mask;
        const float o2 = q2 + (float)w2 * mask;
        out[OUT1 + qi * 3 + 0] = o0; out[OUT1 + qi * 3 + 1] = o1; out[OUT1 + qi * 3 + 2] = o2;
        out[OUT2 + qi * 3 + 0] = o0; out[OUT2 + qi * 3 + 1] = o1; out[OUT2 + qi * 3 + 2] = o2;
    }
}

__global__ __launch_bounds__(256, 8) void k_phase2_f(
        const float* qin, const float* ffq, const float* ffp, const float* R1,
        const float* R2, const int* cent, const float* W, const float* bvec,
        const float* fqn, const float* fpn, const unsigned short* cand, float* out) {
    phase2_body<true>(qin, ffq, ffp, R1, R2, cent, W, bvec,
                      nullptr, nullptr, fqn, fpn, cand, out);
}

__global__ __launch_bounds__(256, 8) void k_phase2_v(
        const float* qin, const float* ffq, const float* ffp, const float* R1,
        const float* R2, const int* cent, const float* W, const float* bvec,
        const float* normq, const float* normp, const unsigned short* cand, float* out) {
    phase2_body<false>(qin, ffq, ffp, R1, R2, cent, W, bvec,
                       normq, normp, nullptr, nullptr, cand, out);
}

extern "C" void kernel_launch(void* const* d_in, const int* in_sizes, int n_in,
                              void* d_out, int out_size, void* d_ws, size_t ws_size,
                              hipStream_t stream) {
    (void)in_sizes; (void)n_in; (void)out_size;
    const float* q   = (const float*)d_in[1];
    const float* ffp = (const float*)d_in[2];
    const float* ffq = (const float*)d_in[3];
    const float* R1  = (const float*)d_in[4];
    const float* R2  = (const float*)d_in[5];
    const int*   ct  = (const int*)d_in[6];
    const float* W   = (const float*)d_in[7];
    const float* bb  = (const float*)d_in[8];
    float* out = (float*)d_out;

    float* normq = (float*)d_ws;                               // BN
    float* normp = normq + BN;                                 // BN
    float* rnp32 = normp + BN;                                 // BN
    unsigned short* cand = (unsigned short*)(rnp32 + BN);      // BN*MM u16
    float* fqn = (float*)(cand + (size_t)BN * MM);             // BN*DD
    float* fpn = fqn + (size_t)BN * DD;                        // BN*DD
    unsigned short* fqb = (unsigned short*)(fpn + (size_t)BN * DD);  // BN*DD u16
    unsigned short* fpb = fqb + (size_t)BN * DD;               // BN*DD u16

    const size_t need = (size_t)BN * (35 * 4 + 2 * DD * 4 + 2 * DD * 2);

    k_norm_np<<<dim3((2 * BN) / 32), dim3(256), 0, stream>>>(ffq, ffp, normq, normp, rnp32);

    if (ws_size >= need) {
        k_normalize<<<dim3((BN * DD) / 1024), dim3(256), 0, stream>>>(
            ffq, ffp, normq, normp, fqn, fpn, fqb, fpb);
        k_phase1_m<<<dim3(BB * (NN / QT) * JSPLIT), dim3(256), 0, stream>>>(fqb, fpb, cand);
        k_phase2_f<<<dim3(BB * NN), dim3(256), 0, stream>>>(q, ffq, ffp, R1, R2, ct, W, bb,
                                                            fqn, fpn, cand, out);
    } else {
        k_phase1_v<<<dim3(BB * (NN / QT) * JSPLIT), dim3(256), 0, stream>>>(ffq, ffp, rnp32, cand);
        k_phase2_v<<<dim3(BB * NN), dim3(256), 0, stream>>>(q, ffq, ffp, R1, R2, ct, W, bb,
                                                            normq, normp, cand, out);
    }
}

// Round 16
// 414.095 us; speedup vs baseline: 1.6219x; 1.0306x over previous
//
#include <hip/hip_runtime.h>
#include <math.h>

#define BB 8
#define NN 2048
#define DD 512
#define KK 16
#define BN (BB*NN)

#define QT 64
#define JSPLIT 4
#define JRANGE (NN/JSPLIT)      // 512 candidates per block
#define MM (16*JSPLIT)          // 64 candidates per query into phase-2
#define SIMP 68                 // simb row stride (floats)

#define KSPLIT 384              // OpenBLAS SGEMM_DEFAULT_Q (ZEN) — DO NOT CHANGE

#define OUT1 (BN*3)
#define OUT2 (2*BN*3)
#define OUT3 (3*BN*3)

typedef __attribute__((ext_vector_type(8))) short bf16x8;
typedef __attribute__((ext_vector_type(4))) float f32x4;

__device__ inline unsigned short cvt_bf16(float f) {   // RNE, finite inputs
    unsigned int u = __float_as_uint(f);
    return (unsigned short)((u + 0x7fffu + ((u >> 16) & 1u)) >> 16);
}

// async global->LDS, 16B per lane; lds must be wave-uniform base (HW adds lane*16)
__device__ inline void gload_lds16(const unsigned short* g, unsigned short* lds) {
    __builtin_amdgcn_global_load_lds((const __attribute__((address_space(1))) void*)g,
                                     (__attribute__((address_space(3))) void*)lds,
                                     16, 0, 0);
}

// ---------------- Kernel 1 (fallback path): numpy-bit-exact f32 row norms -----
// VERIFIED r8. DO NOT CHANGE ARITHMETIC.
__global__ __launch_bounds__(256) void k_norm_np(const float* __restrict__ ffq,
                                                 const float* __restrict__ ffp,
                                                 float* __restrict__ normq,
                                                 float* __restrict__ normp,
                                                 float* __restrict__ rnp32) {
    const int row = blockIdx.x * 32 + (threadIdx.x >> 3);
    const int j   = threadIdx.x & 7;
    const bool isQ = row < BN;
    const int r = isQ ? row : row - BN;
    const float* x = (isQ ? ffq : ffp) + (size_t)r * DD;

    float B[4];
#pragma unroll
    for (int t = 0; t < 4; ++t) {
        const float* xb = x + t * 128;
        float e = xb[j];
        float rj = __fmul_rn(e, e);
#pragma unroll
        for (int i = 1; i < 16; ++i) {
            float v = xb[8 * i + j];
            rj = __fadd_rn(rj, __fmul_rn(v, v));
        }
        float s = __fadd_rn(rj, __shfl_xor(rj, 1, 8));
        float u = __fadd_rn(s,  __shfl_xor(s,  2, 8));
        float w = __fadd_rn(u,  __shfl_xor(u,  4, 8));
        B[t] = w;
    }
    if (j == 0) {
        float norm2 = __fadd_rn(__fadd_rn(B[0], B[1]), __fadd_rn(B[2], B[3]));
        float nrm = __fsqrt_rn(norm2);
        if (isQ) { normq[r] = nrm; }
        else {
            normp[r] = nrm;
            rnp32[r] = 1.0f / __fadd_rn(nrm, 1e-8f);
        }
    }
}

// ---------------- Kernel 1f (fast path): fused norm + normalize ---------------
// r22: replaces k_norm_np + k_normalize on the fast path. 16 rows staged
// into LDS via coalesced float4 (one HBM read instead of two); the r8 norm
// is computed FROM THE LDS COPY with the identical 8-lane scalar reads and
// shuffle butterfly -> bit-identical nrm. Normalization __fdiv_rn(v,den),
// den=__fadd_rn(nrm,1e-8) and bf16 cvt are op-identical to old k_normalize
// -> fpn/fqb/fpb bit-identical. fqn is DROPPED (its only consumer, phase-2
// sfqn, now recomputes the same __fdiv_rn from ffq+normq -> same bits).
__global__ __launch_bounds__(256) void k_norm_fused(
        const float* __restrict__ ffq, const float* __restrict__ ffp,
        float* __restrict__ normq, float* __restrict__ normp,
        float* __restrict__ rnp32, float* __restrict__ fpn,
        unsigned short* __restrict__ fqb, unsigned short* __restrict__ fpb) {
    __shared__ __align__(16) float rows[16 * DD];   // 32 KB
    __shared__ float snrm[16];
    const bool isQ = (int)blockIdx.x < (BN / 16);
    const int r0 = (isQ ? blockIdx.x : blockIdx.x - BN / 16) * 16;
    const float* src = (isQ ? ffq : ffp) + (size_t)r0 * DD;
    const int tid = threadIdx.x;

    // Phase A: coalesced copy 16 rows -> LDS (2048 float4)
    {
        const float4* s4 = (const float4*)src;
        float4* d4 = (float4*)rows;
#pragma unroll
        for (int k = 0; k < 8; ++k)
            d4[tid + k * 256] = s4[tid + k * 256];
    }
    __syncthreads();

    // Phase B: bit-exact r8 norm (threads 0..127: 8 lanes x 16 rows)
    if (tid < 128) {
        const int row = tid >> 3, j = tid & 7;
        const float* x = &rows[row * DD];
        float B[4];
#pragma unroll
        for (int t = 0; t < 4; ++t) {
            const float* xb = x + t * 128;
            float e = xb[j];
            float rj = __fmul_rn(e, e);
#pragma unroll
            for (int i = 1; i < 16; ++i) {
                float v = xb[8 * i + j];
                rj = __fadd_rn(rj, __fmul_rn(v, v));
            }
            float s = __fadd_rn(rj, __shfl_xor(rj, 1, 8));
            float u = __fadd_rn(s,  __shfl_xor(s,  2, 8));
            float w = __fadd_rn(u,  __shfl_xor(u,  4, 8));
            B[t] = w;
        }
        if (j == 0) {
            float norm2 = __fadd_rn(__fadd_rn(B[0], B[1]), __fadd_rn(B[2], B[3]));
            float nrm = __fsqrt_rn(norm2);
            snrm[row] = nrm;
            const int rg = r0 + row;
            if (isQ) { normq[rg] = nrm; }
            else {
                normp[rg] = nrm;
                rnp32[rg] = 1.0f / __fadd_rn(nrm, 1e-8f);
            }
        }
    }
    __syncthreads();

    // Phase C: normalize + coalesced float4/ushort4 stores
    const float4* r4 = (const float4*)rows;
#pragma unroll
    for (int k = 0; k < 8; ++k) {
        const int pos = tid + k * 256;       // float4 index in [0,2048)
        const int row = pos >> 7;
        const float den = __fadd_rn(snrm[row], 1e-8f);
        float4 v = r4[pos];
        float4 o;
        o.x = __fdiv_rn(v.x, den); o.y = __fdiv_rn(v.y, den);
        o.z = __fdiv_rn(v.z, den); o.w = __fdiv_rn(v.w, den);
        ushort4 b4;
        b4.x = cvt_bf16(o.x); b4.y = cvt_bf16(o.y);
        b4.z = cvt_bf16(o.z); b4.w = cvt_bf16(o.w);
        const size_t e4 = (size_t)r0 * DD + (size_t)pos * 4;
        if (isQ) {
            *(ushort4*)(fqb + e4) = b4;
        } else {
            *(float4*)(fpn + e4) = o;
            *(ushort4*)(fpb + e4) = b4;
        }
    }
}

// ---------------- Kernel 2 (fast): bf16 MFMA scoring + per-split top-16 -------
// r16/r17/r18 structure (measured optimum: drain loop CK=128, per-chunk A
// frags with opaque offset, bitonic u64 top-16). r21: original block decode
// (phase-1 XCD remap reverted; phase-2 keeps its measured-good remap).
// C layout (m89): col=lane&15, row=(lane>>4)*4+reg.
#define CK 128                   // staged K-chunk (bf16 elems); DD/CK = 4
__global__ __launch_bounds__(256, 4) void k_phase1_m(const unsigned short* __restrict__ fqb,
                                                     const unsigned short* __restrict__ fpb,
                                                     unsigned short* __restrict__ cand) {
    __shared__ __align__(16) float simb[QT * SIMP];
    __shared__ __align__(16) unsigned short Bst[64 * CK];   // 16 KB staged B chunk

    const int b  = blockIdx.x & 7;
    const int i0 = ((blockIdx.x >> 3) & 31) * QT;
    const int js = blockIdx.x >> 8;
    const int tid = threadIdx.x;
    const int w = tid >> 6, lane = tid & 63;
    const int n16 = lane & 15, quad = lane >> 4;

    const unsigned short* Aq = fqb + ((size_t)b * NN + i0 + w * 16 + n16) * DD + quad * 8;

    // running top-16 as packed keys, ascending (slot 15 = best). 0 = -inf.
    unsigned long long ktop[16];
#pragma unroll
    for (int r = 0; r < 16; ++r) ktop[r] = 0ull;

    const int qq = tid >> 2;
    const int st = tid & 3;
    const size_t bNN = (size_t)b * NN;

    for (int jt = 0; jt < JRANGE / 64; ++jt) {   // 8 j-tiles of 64
        const int j0g = js * JRANGE + jt * 64;

        f32x4 acc[4];
#pragma unroll
        for (int ct = 0; ct < 4; ++ct) acc[ct] = (f32x4){0.f, 0.f, 0.f, 0.f};

        for (int kc = 0; kc < 4; ++kc) {          // K chunks of 128
            __syncthreads();   // prev chunk's ds_reads / prev tile's sel reads done
            // stage: call l covers LDS rows (w*4+l)*4+quad, block col n16
            // data at LDS block (r, n16) comes from global block (r, n16^(r&15))
#pragma unroll
            for (int l = 0; l < 4; ++l) {
                const int r  = (w * 4 + l) * 4 + quad;
                const int sb = n16 ^ (r & 15);
                const unsigned short* gsrc =
                    fpb + (bNN + j0g + r) * DD + kc * CK + sb * 8;
                gload_lds16(gsrc, &Bst[(w * 4 + l) * 512]);   // 1 KB per call
            }
            // A frags for this chunk only (opaque offset: not hoistable).
            int koff = kc * 128;
            asm volatile("" : "+v"(koff));
            bf16x8 a0 = *(const bf16x8*)(Aq + koff);
            bf16x8 a1 = *(const bf16x8*)(Aq + koff + 32);
            bf16x8 a2 = *(const bf16x8*)(Aq + koff + 64);
            bf16x8 a3 = *(const bf16x8*)(Aq + koff + 96);
            __syncthreads();   // barrier drains vmcnt -> LDS chunk + A frags ready
#pragma unroll
            for (int k4 = 0; k4 < 4; ++k4) {
                const bf16x8 af = (k4 == 0) ? a0 : (k4 == 1) ? a1 : (k4 == 2) ? a2 : a3;
#pragma unroll
                for (int ct = 0; ct < 4; ++ct) {
                    const int r  = ct * 16 + n16;
                    const int cb = (k4 * 4 + quad) ^ (r & 15);
                    bf16x8 bfr = *(const bf16x8*)&Bst[r * CK + cb * 8];
                    acc[ct] = __builtin_amdgcn_mfma_f32_16x16x32_bf16(
                        af, bfr, acc[ct], 0, 0, 0);
                }
            }
        }

        __syncthreads();
#pragma unroll
        for (int ct = 0; ct < 4; ++ct)
#pragma unroll
            for (int r = 0; r < 4; ++r)
                simb[(w * 16 + quad * 4 + r) * SIMP + ct * 16 + n16] = acc[ct][r];
        __syncthreads();

        // ---- r18 selection: branchless bitonic top-16 on packed u64 keys ----
        unsigned long long nk[16];
#pragma unroll
        for (int t4 = 0; t4 < 4; ++t4) {
            const float4 v4 = *(const float4*)&simb[qq * SIMP + st * 16 + t4 * 4];
            const float vv[4] = {v4.x, v4.y, v4.z, v4.w};
#pragma unroll
            for (int u = 0; u < 4; ++u) {
                const float cvf = __fadd_rn(vv[u], 0.0f);     // -0 -> +0
                const unsigned int ub  = __float_as_uint(cvf);
                const unsigned int ord = ub ^ (((unsigned int)((int)ub >> 31)) | 0x80000000u);
                const unsigned int jg  = (unsigned int)(j0g + st * 16 + t4 * 4 + u);
                nk[t4 * 4 + u] = ((unsigned long long)ord << 32)
                               | (unsigned long long)(~jg);
            }
        }
#pragma unroll
        for (int k = 2; k <= 16; k <<= 1) {
#pragma unroll
            for (int j = k >> 1; j > 0; j >>= 1) {
#pragma unroll
                for (int i = 0; i < 16; ++i) {
                    const int l = i ^ j;
                    if (l > i) {
                        const bool up = ((i & k) == 0);
                        const unsigned long long a = nk[i], bq = nk[l];
                        const bool sw = up ? (a > bq) : (a < bq);
                        nk[i] = sw ? bq : a;
                        nk[l] = sw ? a : bq;
                    }
                }
            }
        }
        unsigned long long mg[16];
#pragma unroll
        for (int i = 0; i < 16; ++i) {
            const unsigned long long a = ktop[i], bq = nk[15 - i];
            mg[i] = (a > bq) ? a : bq;
        }
#pragma unroll
        for (int j = 8; j > 0; j >>= 1) {
#pragma unroll
            for (int i = 0; i < 16; ++i) {
                const int l = i ^ j;
                if (l > i) {
                    const unsigned long long a = mg[i], bq = mg[l];
                    const bool sw = a > bq;
                    mg[i] = sw ? bq : a;
                    mg[l] = sw ? a : bq;
                }
            }
        }
#pragma unroll
        for (int i = 0; i < 16; ++i) ktop[i] = mg[i];
    }

    // merge 4 sorted 16-lists (lanes st=0..3 of query qq) -> split top-16.
    __syncthreads();
    int p = 15;
    const size_t base = ((size_t)b * NN + i0 + qq) * MM + (size_t)js * 16;
    for (int m = 0; m < 16; ++m) {
        const unsigned long long myk = (p >= 0) ? ktop[p] : 0ull;
        unsigned long long wk = myk;
        unsigned long long ok;
        ok = __shfl_xor(wk, 1, 4); if (ok > wk) wk = ok;
        ok = __shfl_xor(wk, 2, 4); if (ok > wk) wk = ok;
        if (p >= 0 && myk == wk) --p;
        if (st == 0) cand[base + m] = (unsigned short)(~(unsigned int)wk);
    }
}

// ---------------- Kernel 2 (fallback): r9 fp32 GEMM phase-1 -------------------
#define JTILE 64
#define BK 16
#define LDP 68
__global__ __launch_bounds__(256, 4) void k_phase1_v(const float* __restrict__ ffq,
                                                     const float* __restrict__ ffp,
                                                     const float* __restrict__ rnp32,
                                                     unsigned short* __restrict__ cand) {
    __shared__ __align__(16) float As[BK * LDP];
    __shared__ __align__(16) float Bs[BK * LDP];
    __shared__ __align__(16) float simb[QT * SIMP];

    const int b  = blockIdx.x & 7;
    const int i0 = ((blockIdx.x >> 3) & 31) * QT;
    const int js = blockIdx.x >> 8;
    const int tid = threadIdx.x;
    const int tx = tid & 15, ty = tid >> 4;

    const float* Abase = ffq + ((size_t)b * NN + i0) * DD;
    const float* Bbase = ffp + (size_t)b * NN * DD;

    float tv[16]; int tix[16];
#pragma unroll
    for (int r = 0; r < 16; ++r) { tv[r] = -INFINITY; tix[r] = -1; }

    const int lrow = tid >> 2;
    const int lseg = (tid & 3) * 4;
    const int qq = tid >> 2;
    const int st = tid & 3;

    for (int jt = 0; jt < JRANGE / JTILE; ++jt) {
        const int j0 = js * JRANGE + jt * JTILE;
        float acc[4][4];
#pragma unroll
        for (int r = 0; r < 4; ++r)
#pragma unroll
            for (int c = 0; c < 4; ++c) acc[r][c] = 0.0f;

        for (int kt = 0; kt < DD / BK; ++kt) {
            const int k0 = kt * BK;
            __syncthreads();
            float4 av = *(const float4*)(Abase + (size_t)lrow * DD + k0 + lseg);
            float4 bv = *(const float4*)(Bbase + (size_t)(j0 + lrow) * DD + k0 + lseg);
            As[(lseg + 0) * LDP + lrow] = av.x; As[(lseg + 1) * LDP + lrow] = av.y;
            As[(lseg + 2) * LDP + lrow] = av.z; As[(lseg + 3) * LDP + lrow] = av.w;
            Bs[(lseg + 0) * LDP + lrow] = bv.x; Bs[(lseg + 1) * LDP + lrow] = bv.y;
            Bs[(lseg + 2) * LDP + lrow] = bv.z; Bs[(lseg + 3) * LDP + lrow] = bv.w;
            __syncthreads();
#pragma unroll
            for (int kk = 0; kk < BK; ++kk) {
                const float4 a4 = *(const float4*)&As[kk * LDP + ty * 4];
                const float4 b4 = *(const float4*)&Bs[kk * LDP + tx * 4];
                const float ar[4] = {a4.x, a4.y, a4.z, a4.w};
                const float br[4] = {b4.x, b4.y, b4.z, b4.w};
#pragma unroll
                for (int r = 0; r < 4; ++r)
#pragma unroll
                    for (int c = 0; c < 4; ++c)
                        acc[r][c] = fmaf(ar[r], br[c], acc[r][c]);
            }
        }
        float rp[4];
#pragma unroll
        for (int c = 0; c < 4; ++c) rp[c] = rnp32[b * NN + j0 + tx * 4 + c];
#pragma unroll
        for (int r = 0; r < 4; ++r) {
            float4 v4;
            v4.x = acc[r][0] * rp[0]; v4.y = acc[r][1] * rp[1];
            v4.z = acc[r][2] * rp[2]; v4.w = acc[r][3] * rp[3];
            *(float4*)&simb[(ty * 4 + r) * SIMP + tx * 4] = v4;
        }
        __syncthreads();

#pragma unroll
        for (int t = 0; t < 16; ++t) {
            const int jl = st * 16 + t;
            const float v = simb[qq * SIMP + jl];
            const int jg = j0 + jl;
            if (v > tv[0]) {
#pragma unroll
                for (int r = 0; r < 15; ++r) {
                    const bool up = tv[r + 1] < v;
                    const float nv = up ? tv[r + 1] : ((tv[r] < v) ? v : tv[r]);
                    const int   ni = up ? tix[r + 1] : ((tv[r] < v) ? jg : tix[r]);
                    tv[r] = nv; tix[r] = ni;
                }
                if (tv[15] < v) { tv[15] = v; tix[15] = jg; }
            }
        }
        __syncthreads();
    }

    int p = 15;
    const size_t base = ((size_t)b * NN + i0 + qq) * MM + (size_t)js * 16;
    for (int m = 0; m < 16; ++m) {
        float cv = (p >= 0) ? tv[p] : -INFINITY;
        int   ci = (p >= 0) ? tix[p] : -1;
        float ov; int oi;
        ov = __shfl_xor(cv, 1, 4); oi = __shfl_xor(ci, 1, 4);
        if (ov > cv || (ov == cv && (unsigned)oi < (unsigned)ci)) { cv = ov; ci = oi; }
        ov = __shfl_xor(cv, 2, 4); oi = __shfl_xor(ci, 2, 4);
        if (ov > cv || (ov == cv && (unsigned)oi < (unsigned)ci)) { cv = ov; ci = oi; }
        if (p >= 0 && tv[p] == cv && tix[p] == ci) --p;
        if (st == 0) cand[base + m] = (unsigned short)ci;
    }
}

// ---------------- 3x3 inverse (adjugate) apply ----------------
__device__ inline void inv3_apply(const double* a, double x0, double x1, double x2,
                                  double& y0, double& y1, double& y2) {
    double c00 = a[4]*a[8] - a[5]*a[7];
    double c01 = a[2]*a[7] - a[1]*a[8];
    double c02 = a[1]*a[5] - a[2]*a[4];
    double c10 = a[5]*a[6] - a[3]*a[8];
    double c11 = a[0]*a[8] - a[2]*a[6];
    double c12 = a[2]*a[3] - a[0]*a[5];
    double c20 = a[3]*a[7] - a[4]*a[6];
    double c21 = a[1]*a[6] - a[0]*a[7];
    double c22 = a[0]*a[4] - a[1]*a[3];
    double det = a[0]*c00 + a[1]*c10 + a[2]*c20;
    double id = 1.0 / det;
    y0 = (c00*x0 + c01*x1 + c02*x2) * id;
    y1 = (c10*x0 + c11*x1 + c12*x2) * id;
    y2 = (c20*x0 + c21*x1 + c22*x2) * id;
}

// =============== shared phase-2 body (templated on normalized source) =========
// VERIFIED r8 arithmetic: two ascending-k FMA chains split at d=384, one
// rounded add. Tie: value desc, index asc. DO NOT CHANGE ARITHMETIC.
//
// r10/r12/r16 structure. r20: XCD remap KEPT (measured 190->176us).
// r22: sfqn computed from ffq+normq in BOTH paths (the exact __fdiv_rn
// sequence that produced fqn -> bit-identical); fqn array dropped.
#define STG_S 67   // LDS stage row stride (floats)
template <bool PRE>   // PRE: normalized fpn precomputed (fast path)
__device__ inline void phase2_body(
        const float* __restrict__ qin, const float* __restrict__ ffq,
        const float* __restrict__ ffp, const float* __restrict__ R1,
        const float* __restrict__ R2, const int* __restrict__ cent,
        const float* __restrict__ W, const float* __restrict__ bvec,
        const float* __restrict__ normq, const float* __restrict__ normp,
        const float* __restrict__ fpn,
        const unsigned short* __restrict__ cand, float* __restrict__ out) {
    static_assert(KSPLIT == 384, "chunk split at c=6 assumes KSPLIT==384");
    static_assert(MM * STG_S >= 2 * DD, "meanf/maxf overlay needs 2*DD floats");
    const unsigned int wg = ((blockIdx.x & 7u) << 11) | (blockIdx.x >> 3);  // r20
    const int b = (int)(wg >> 11);
    const int i = (int)(wg & 2047u);
    const int tid = threadIdx.x;
    const size_t qi = (size_t)b * NN + i;

    __shared__ float sfqn[DD];
    __shared__ int cj[MM];
    __shared__ float pden_s[MM];
    __shared__ float sv[MM];
    __shared__ int sel[KK];
    __shared__ __align__(16) float stg[MM * STG_S];   // 16.75 KB stage buffer
    __shared__ float red[3][4];
    // stg is dead after the rescore chains; reuse it for mean/max pooling.
    float* const meanf = stg;
    float* const maxf  = stg + DD;

    {
        const float qden = __fadd_rn(normq[qi], 1e-8f);
        for (int d = tid; d < DD; d += 256)
            sfqn[d] = __fdiv_rn(ffq[qi * DD + d], qden);
    }
    if (tid < MM) {
        int j = (int)cand[qi * MM + tid];
        cj[tid] = j;
        if (!PRE) pden_s[tid] = __fadd_rn(normp[(size_t)b * NN + j], 1e-8f);
    }
    __syncthreads();

    // ---- rescore: reg-prefetch pipelined LDS staging, bit-exact chains ----
    const int srow = tid >> 2;          // 0..63: candidate row this thread helps stage
    const int slan = tid & 3;           // 4 lanes x float4 = 64B contiguous per row
    const float* fprow = (PRE ? fpn : ffp) + ((size_t)b * NN + cj[srow]) * DD;
    const float pd = (!PRE) ? pden_s[tid < MM ? tid : 0] : 1.0f;
    float acc1 = 0.0f, acc2 = 0.0f;

    auto stg_write = [&](const float4* P) {
#pragma unroll
        for (int i4 = 0; i4 < 4; ++i4) {
            const int off = srow * STG_S + i4 * 16 + slan * 4;
            stg[off + 0] = P[i4].x; stg[off + 1] = P[i4].y;
            stg[off + 2] = P[i4].z; stg[off + 3] = P[i4].w;
        }
    };
    auto ld_chunk = [&](float4* P, int c) {
#pragma unroll
        for (int i4 = 0; i4 < 4; ++i4)
            P[i4] = *(const float4*)(fprow + c * 64 + i4 * 16 + slan * 4);
    };
    auto chain = [&](int c, float& acc) {
        const int d0 = c * 64;
        const float* s = stg + tid * STG_S;
        if (PRE) {
#pragma unroll
            for (int k = 0; k < 64; ++k)
                acc = fmaf(sfqn[d0 + k], s[k], acc);
        } else {
#pragma unroll
            for (int k = 0; k < 64; ++k)
                acc = fmaf(sfqn[d0 + k], __fdiv_rn(s[k], pd), acc);
        }
    };

    float4 pA[4], pB[4];
    ld_chunk(pA, 0);
#pragma unroll
    for (int ch = 0; ch < 4; ++ch) {
        // ---- even chunk c0 = 2*ch: stg <- pA, prefetch c0+1 -> pB ----
        {
            const int c0 = 2 * ch;
            stg_write(pA);
            ld_chunk(pB, c0 + 1);               // always valid (c0+1 <= 7)
            __syncthreads();
            if (tid < MM) chain(c0, (c0 < 6) ? acc1 : acc2);
            __syncthreads();                     // chain reads done before overwrite
        }
        // ---- odd chunk c1 = 2*ch+1: stg <- pB, prefetch c1+1 -> pA ----
        {
            const int c1 = 2 * ch + 1;
            stg_write(pB);
            if (ch < 3) ld_chunk(pA, c1 + 1);    // constant-folded under unroll
            __syncthreads();
            if (tid < MM) chain(c1, (c1 < 6) ? acc1 : acc2);
            __syncthreads();
        }
    }
    if (tid < MM) sv[tid] = __fadd_rn(acc1, acc2);
    __syncthreads();

    if (tid < MM) {
        const float v = sv[tid]; const int jj = cj[tid];
        int rank = 0;
        for (int t = 0; t < MM; ++t) {
            const float vt = sv[t]; const int jo = cj[t];
            rank += (vt > v) || (vt == v && jo < jj);
        }
        if (rank < KK) {
            sel[rank] = jj;
            out[(size_t)OUT3 + qi * KK + rank] = (float)jj;
        }
    }
    __syncthreads();

    for (int d = tid; d < DD; d += 256) {
        float sum = 0.0f, mx = -INFINITY;
#pragma unroll
        for (int k = 0; k < KK; ++k) {
            float v = ffp[((size_t)b * NN + sel[k]) * DD + d];
            sum += v; mx = fmaxf(mx, v);
        }
        meanf[d] = sum * (1.0f / 16.0f);
        maxf[d]  = mx;
    }
    __syncthreads();

    float a0 = 0.f, a1 = 0.f, a2 = 0.f;
    for (int d = tid; d < DD; d += 256) {
        const float x = ffq[qi * DD + d], m = meanf[d], mx = maxf[d];
        a0 = fmaf(W[d],        x, a0); a0 = fmaf(W[512 + d],        m, a0); a0 = fmaf(W[1024 + d],        mx, a0);
        a1 = fmaf(W[1536 + d], x, a1); a1 = fmaf(W[1536 + 512 + d], m, a1); a1 = fmaf(W[1536 + 1024 + d], mx, a1);
        a2 = fmaf(W[3072 + d], x, a2); a2 = fmaf(W[3072 + 512 + d], m, a2); a2 = fmaf(W[3072 + 1024 + d], mx, a2);
    }
#pragma unroll
    for (int off = 32; off > 0; off >>= 1) {
        a0 += __shfl_down(a0, off, 64);
        a1 += __shfl_down(a1, off, 64);
        a2 += __shfl_down(a2, off, 64);
    }
    const int lane = tid & 63, wid = tid >> 6;
    if (lane == 0) { red[0][wid] = a0; red[1][wid] = a1; red[2][wid] = a2; }
    __syncthreads();

    if (tid == 0) {
        double v0 = (double)bvec[0] + red[0][0] + red[0][1] + red[0][2] + red[0][3];
        double v1 = (double)bvec[1] + red[1][0] + red[1][1] + red[1][2] + red[1][3];
        double v2 = (double)bvec[2] + red[2][0] + red[2][1] + red[2][2] + red[2][3];
        double r1[9], r2[9];
#pragma unroll
        for (int t = 0; t < 9; ++t) { r1[t] = R1[qi * 9 + t]; r2[t] = R2[qi * 9 + t]; }
        double u0, u1, u2, w0, w1, w2;
        inv3_apply(r1, v0, v1, v2, u0, u1, u2);
        inv3_apply(r2, u0, u1, u2, w0, w1, w2);
        const float mask = (cent[qi] >= NN) ? 1.0f : 0.0f;
        const float q0 = qin[qi * 3 + 0], q1 = qin[qi * 3 + 1], q2 = qin[qi * 3 + 2];
        out[qi * 3 + 0] = q0; out[qi * 3 + 1] = q1; out[qi * 3 + 2] = q2;
        const float o0 = q0 + (float)w0 * mask;
        const float o1 = q1 + (float)w1 * mask;
        const float o2 = q2 + (float)w2 * mask;
        out[OUT1 + qi * 3 + 0] = o0; out[OUT1 + qi * 3 + 1] = o1; out[OUT1 + qi * 3 + 2] = o2;
        out[OUT2 + qi * 3 + 0] = o0; out[OUT2 + qi * 3 + 1] = o1; out[OUT2 + qi * 3 + 2] = o2;
    }
}

__global__ __launch_bounds__(256, 8) void k_phase2_f(
        const float* qin, const float* ffq, const float* ffp, const float* R1,
        const float* R2, const int* cent, const float* W, const float* bvec,
        const float* normq, const float* fpn, const unsigned short* cand, float* out) {
    phase2_body<true>(qin, ffq, ffp, R1, R2, cent, W, bvec,
                      normq, nullptr, fpn, cand, out);
}

__global__ __launch_bounds__(256, 8) void k_phase2_v(
        const float* qin, const float* ffq, const float* ffp, const float* R1,
        const float* R2, const int* cent, const float* W, const float* bvec,
        const float* normq, const float* normp, const unsigned short* cand, float* out) {
    phase2_body<false>(qin, ffq, ffp, R1, R2, cent, W, bvec,
                       normq, normp, nullptr, cand, out);
}

extern "C" void kernel_launch(void* const* d_in, const int* in_sizes, int n_in,
                              void* d_out, int out_size, void* d_ws, size_t ws_size,
                              hipStream_t stream) {
    (void)in_sizes; (void)n_in; (void)out_size;
    const float* q   = (const float*)d_in[1];
    const float* ffp = (const float*)d_in[2];
    const float* ffq = (const float*)d_in[3];
    const float* R1  = (const float*)d_in[4];
    const float* R2  = (const float*)d_in[5];
    const int*   ct  = (const int*)d_in[6];
    const float* W   = (const float*)d_in[7];
    const float* bb  = (const float*)d_in[8];
    float* out = (float*)d_out;

    float* normq = (float*)d_ws;                               // BN
    float* normp = normq + BN;                                 // BN
    float* rnp32 = normp + BN;                                 // BN
    unsigned short* cand = (unsigned short*)(rnp32 + BN);      // BN*MM u16
    float* fqn = (float*)(cand + (size_t)BN * MM);             // BN*DD (unused, slot kept)
    float* fpn = fqn + (size_t)BN * DD;                        // BN*DD
    unsigned short* fqb = (unsigned short*)(fpn + (size_t)BN * DD);  // BN*DD u16
    unsigned short* fpb = fqb + (size_t)BN * DD;               // BN*DD u16

    const size_t need = (size_t)BN * (35 * 4 + 2 * DD * 4 + 2 * DD * 2);

    if (ws_size >= need) {
        k_norm_fused<<<dim3(2 * BN / 16), dim3(256), 0, stream>>>(
            ffq, ffp, normq, normp, rnp32, fpn, fqb, fpb);
        k_phase1_m<<<dim3(BB * (NN / QT) * JSPLIT), dim3(256), 0, stream>>>(fqb, fpb, cand);
        k_phase2_f<<<dim3(BB * NN), dim3(256), 0, stream>>>(q, ffq, ffp, R1, R2, ct, W, bb,
                                                            normq, fpn, cand, out);
    } else {
        k_norm_np<<<dim3((2 * BN) / 32), dim3(256), 0, stream>>>(ffq, ffp, normq, normp, rnp32);
        k_phase1_v<<<dim3(BB * (NN / QT) * JSPLIT), dim3(256), 0, stream>>>(ffq, ffp, rnp32, cand);
        k_phase2_v<<<dim3(BB * NN), dim3(256), 0, stream>>>(q, ffq, ffp, R1, R2, ct, W, bb,
                                                            normq, normp, cand, out);
    }
}